// Round 1
// baseline (691.940 us; speedup 1.0000x reference)
//
#include <hip/hip_runtime.h>
#include <stdint.h>
#include <stddef.h>

// Problem constants
#define B_   8
#define N_   8192
#define S_   2048
#define D_   256
#define M_   (B_*N_)     // 65536 total points
#define C0_  256         // MLP[0]
#define C1_  128         // MLP[1]
#define K2D_ 512         // 2*D

typedef __attribute__((ext_vector_type(8))) short short8;
typedef __attribute__((ext_vector_type(4))) float f32x4;

__device__ __forceinline__ short f2bf(float f) {
  unsigned u = __float_as_uint(f);
  u += 0x7fffu + ((u >> 16) & 1u);   // round-to-nearest-even
  return (short)(u >> 16);
}

__device__ __forceinline__ void cp16(const void* g, void* l) {
  __builtin_amdgcn_global_load_lds(
      (__attribute__((address_space(1))) void*)(g),
      (__attribute__((address_space(3))) void*)(l), 16, 0, 0);
}

// ---------------------------------------------------------------------------
// K0: convert W0 / W1 to bf16
// ---------------------------------------------------------------------------
__global__ void convw_kernel(const float* __restrict__ W0,
                             const float* __restrict__ W1,
                             short* __restrict__ W0b, short* __restrict__ W1b) {
  int i = blockIdx.x * 256 + threadIdx.x;
  if (i < C0_ * K2D_) W0b[i] = f2bf(W0[i]);
  if (i < C1_ * C0_)  W1b[i] = f2bf(W1[i]);
}

// ---------------------------------------------------------------------------
// K1: top-3 nearest neighbors + sigmoid relation weights (pre-divided by 3)
// Distance replicated bit-exactly like numpy: (s1 + s2) - 2*((ax*bx+ay*by)+az*bz)
// ---------------------------------------------------------------------------
__global__ __launch_bounds__(256, 1)
void topk_kernel(const float* __restrict__ xyz1, const float* __restrict__ xyz2,
                 const float* __restrict__ relw, const float* __restrict__ relb,
                 int* __restrict__ idx_out, float* __restrict__ w_out) {
  __shared__ float4 s2[S_];  // x,y,z,sumsq  (32 KB)
  const int b = blockIdx.x >> 5;          // 32 blocks per batch
  const int n = (blockIdx.x & 31) * 256 + threadIdx.x;

  for (int s = threadIdx.x; s < S_; s += 256) {
    float x = xyz2[((size_t)b * S_ + s) * 3 + 0];
    float y = xyz2[((size_t)b * S_ + s) * 3 + 1];
    float z = xyz2[((size_t)b * S_ + s) * 3 + 2];
    float ss = __fadd_rn(__fadd_rn(__fmul_rn(x, x), __fmul_rn(y, y)), __fmul_rn(z, z));
    s2[s] = make_float4(x, y, z, ss);
  }
  __syncthreads();

  const float* p = xyz1 + ((size_t)b * N_ + n) * 3;
  const float ax = p[0], ay = p[1], az = p[2];
  const float s1 = __fadd_rn(__fadd_rn(__fmul_rn(ax, ax), __fmul_rn(ay, ay)), __fmul_rn(az, az));

  float d0 = 3.4e38f, d1 = 3.4e38f, d2 = 3.4e38f;
  int   i0 = 0, i1 = 0, i2 = 0;
  #pragma unroll 4
  for (int s = 0; s < S_; s++) {
    float4 q = s2[s];
    float dot = __fadd_rn(__fadd_rn(__fmul_rn(ax, q.x), __fmul_rn(ay, q.y)), __fmul_rn(az, q.z));
    float d = __fsub_rn(__fadd_rn(s1, q.w), __fmul_rn(2.0f, dot));
    if (d < d2) {
      if (d < d1) {
        d2 = d1; i2 = i1;
        if (d < d0) { d1 = d0; i1 = i0; d0 = d; i0 = s; }
        else        { d1 = d;  i1 = s; }
      } else { d2 = d; i2 = s; }
    }
  }

  const float w0r = relw[0], w1r = relw[1], w2r = relw[2], w3r = relw[3], br = relb[0];
  const size_t base = ((size_t)b * N_ + n) * 3;
  float dd[3] = {d0, d1, d2};
  int   ii[3] = {i0, i1, i2};
  #pragma unroll
  for (int k = 0; k < 3; k++) {
    float4 q = s2[ii[k]];
    float ox = ax - q.x, oy = ay - q.y, oz = az - q.z;
    float t = dd[k] * w0r + ox * w1r + oy * w2r + oz * w3r + br;
    float w = 1.0f / (1.0f + expf(-t));
    idx_out[base + k] = ii[k];
    w_out[base + k] = w * (1.0f / 3.0f);
  }
}

// ---------------------------------------------------------------------------
// K2: build h = [points1 | sum_k w_k*points2[idx_k]] as bf16, [M][512]
// ---------------------------------------------------------------------------
__global__ __launch_bounds__(256, 1)
void build_h_kernel(const float* __restrict__ p1, const float* __restrict__ p2,
                    const int* __restrict__ idx, const float* __restrict__ wts,
                    short* __restrict__ h) {
  const int row = blockIdx.x;
  const int c = threadIdx.x;
  const int b = row >> 13;   // /8192
  const int i0 = idx[row * 3 + 0], i1 = idx[row * 3 + 1], i2 = idx[row * 3 + 2];
  const float w0 = wts[row * 3 + 0], w1 = wts[row * 3 + 1], w2 = wts[row * 3 + 2];
  const float* pb = p2 + (size_t)b * S_ * D_;
  float v = w0 * pb[(size_t)i0 * D_ + c] + w1 * pb[(size_t)i1 * D_ + c] + w2 * pb[(size_t)i2 * D_ + c];
  h[(size_t)row * K2D_ + c]        = f2bf(p1[(size_t)row * D_ + c]);
  h[(size_t)row * K2D_ + D_ + c]   = f2bf(v);
}

// ---------------------------------------------------------------------------
// GEMM: C[M][Nout] = A[M][KTOT](bf16) @ Bw[Nout][KTOT]^T(bf16) + bias
// 128x128 tile per block, 4 waves (2x2), each wave 64x64 via 4x4 MFMA frags.
// ---------------------------------------------------------------------------
template <int KTOT>
__global__ __launch_bounds__(256, 1)
void gemm_bt_kernel(const short* __restrict__ A, const short* __restrict__ Bw,
                    const float* __restrict__ bias, float* __restrict__ C,
                    const int Nout) {
  __shared__ __align__(16) short sA[128 * 32];
  __shared__ __align__(16) short sB[128 * 32];
  const int tid = threadIdx.x;
  const int lane = tid & 63;
  const int wave = tid >> 6;
  const int wm = wave & 1;
  const int wn = wave >> 1;
  const size_t mbase = (size_t)blockIdx.x * 128;
  const int nbase = blockIdx.y * 128;

  const int lrow = lane >> 2;          // 0..15
  const int lcol = (lane & 3) * 8;     // 0,8,16,24

  f32x4 acc[4][4] = {};

  for (int k0 = 0; k0 < KTOT; k0 += 32) {
    #pragma unroll
    for (int t = 0; t < 2; t++) {
      const int r = wave * 32 + t * 16;
      cp16(A  + (mbase + r + lrow) * KTOT + k0 + lcol, &sA[r * 32]);
      cp16(Bw + (size_t)(nbase + r + lrow) * KTOT + k0 + lcol, &sB[r * 32]);
    }
    __syncthreads();

    const int mr = lane & 15;
    const int ks = (lane >> 4) * 8;
    short8 af[4], bfr[4];
    #pragma unroll
    for (int i = 0; i < 4; i++) af[i]  = *(const short8*)&sA[(wm * 64 + i * 16 + mr) * 32 + ks];
    #pragma unroll
    for (int j = 0; j < 4; j++) bfr[j] = *(const short8*)&sB[(wn * 64 + j * 16 + mr) * 32 + ks];
    #pragma unroll
    for (int i = 0; i < 4; i++)
      #pragma unroll
      for (int j = 0; j < 4; j++)
        acc[i][j] = __builtin_amdgcn_mfma_f32_16x16x32_bf16(af[i], bfr[j], acc[i][j], 0, 0, 0);
    __syncthreads();
  }

  const int cr = (lane >> 4) * 4;
  const int cc = lane & 15;
  #pragma unroll
  for (int i = 0; i < 4; i++) {
    #pragma unroll
    for (int j = 0; j < 4; j++) {
      const int col = nbase + wn * 64 + j * 16 + cc;
      const float bv = bias[col];
      #pragma unroll
      for (int r = 0; r < 4; r++) {
        const size_t row = mbase + wm * 64 + i * 16 + cr + r;
        C[row * Nout + col] = acc[i][j][r] + bv;
      }
    }
  }
}

// ---------------------------------------------------------------------------
// Stats: per-channel partial sums over 256-row chunks (deterministic)
// ---------------------------------------------------------------------------
__global__ void stats_partial_kernel(const float* __restrict__ a, float* __restrict__ pp,
                                     const int C, const int rows_per_block) {
  const int c = threadIdx.x;     // blockDim.x == C
  const size_t r0 = (size_t)blockIdx.x * rows_per_block;
  float s = 0.f, s2 = 0.f;
  for (int r = 0; r < rows_per_block; r++) {
    float v = a[(r0 + r) * C + c];
    s += v; s2 += v * v;
  }
  pp[(size_t)blockIdx.x * 2 * C + c]     = s;
  pp[(size_t)blockIdx.x * 2 * C + C + c] = s2;
}

__global__ void stats_final_kernel(const float* __restrict__ pp, const int nparts, const int C,
                                   const float* __restrict__ g, const float* __restrict__ be,
                                   float* __restrict__ ss) {
  const int c = threadIdx.x;
  if (c >= C) return;
  float s = 0.f, s2 = 0.f;
  for (int p = 0; p < nparts; p++) {
    s  += pp[(size_t)p * 2 * C + c];
    s2 += pp[(size_t)p * 2 * C + C + c];
  }
  const float inv = 1.0f / (float)M_;
  float mean = s * inv;
  float var = s2 * inv - mean * mean;
  float sc = g[c] * rsqrtf(var + 1e-5f);
  ss[c] = sc;
  ss[C + c] = be[c] - mean * sc;
}

// ---------------------------------------------------------------------------
// Normalize + ReLU
// ---------------------------------------------------------------------------
__global__ void norm1_kernel(const float* __restrict__ a, const float* __restrict__ ss,
                             short* __restrict__ h1) {
  const size_t i = (size_t)blockIdx.x * 256 + threadIdx.x;
  const int c = threadIdx.x;   // C0_ == 256 == blockDim
  float v = a[i] * ss[c] + ss[C0_ + c];
  v = v > 0.f ? v : 0.f;
  h1[i] = f2bf(v);
}

__global__ void norm2_kernel(float* __restrict__ out, const float* __restrict__ ss) {
  const size_t i = (size_t)blockIdx.x * 256 + threadIdx.x;
  const int c = (int)(i & (C1_ - 1));
  float v = out[i] * ss[c] + ss[C1_ + c];
  out[i] = v > 0.f ? v : 0.f;
}

// ---------------------------------------------------------------------------
// Launch
// ---------------------------------------------------------------------------
extern "C" void kernel_launch(void* const* d_in, const int* in_sizes, int n_in,
                              void* d_out, int out_size, void* d_ws, size_t ws_size,
                              hipStream_t stream) {
  const float* xyz1 = (const float*)d_in[0];
  const float* xyz2 = (const float*)d_in[1];
  const float* pts1 = (const float*)d_in[2];
  const float* pts2 = (const float*)d_in[3];
  const float* relw = (const float*)d_in[4];
  const float* relb = (const float*)d_in[5];
  const float* W0   = (const float*)d_in[6];
  const float* b0   = (const float*)d_in[7];
  const float* g0   = (const float*)d_in[8];
  const float* be0  = (const float*)d_in[9];
  const float* W1   = (const float*)d_in[10];
  const float* b1   = (const float*)d_in[11];
  const float* g1   = (const float*)d_in[12];
  const float* be1  = (const float*)d_in[13];

  char* ws = (char*)d_ws;
  constexpr size_t IDX_OFF = 0;                                    // 65536*3 int
  constexpr size_t WTS_OFF = IDX_OFF + (size_t)M_ * 3 * 4;         // 65536*3 f32
  constexpr size_t W0B_OFF = WTS_OFF + (size_t)M_ * 3 * 4;         // 256*512 bf16
  constexpr size_t W1B_OFF = W0B_OFF + (size_t)C0_ * K2D_ * 2;     // 128*256 bf16
  constexpr size_t H_OFF   = W1B_OFF + (size_t)C1_ * C0_ * 2;      // M*512 bf16
  constexpr size_t A1_OFF  = H_OFF + (size_t)M_ * K2D_ * 2;        // M*256 f32
  constexpr size_t H1_OFF  = A1_OFF + (size_t)M_ * C0_ * 4;        // M*256 bf16
  constexpr size_t PP1_OFF = H1_OFF + (size_t)M_ * C0_ * 2;        // 256*2*256 f32
  constexpr size_t PP2_OFF = PP1_OFF + (size_t)256 * 2 * C0_ * 4;  // 256*2*128 f32
  constexpr size_t SS1_OFF = PP2_OFF + (size_t)256 * 2 * C1_ * 4;  // 2*256 f32
  constexpr size_t SS2_OFF = SS1_OFF + (size_t)2 * C0_ * 4;        // 2*128 f32

  int*   idx = (int*)(ws + IDX_OFF);
  float* wts = (float*)(ws + WTS_OFF);
  short* W0b = (short*)(ws + W0B_OFF);
  short* W1b = (short*)(ws + W1B_OFF);
  short* h   = (short*)(ws + H_OFF);
  float* a1  = (float*)(ws + A1_OFF);
  short* h1  = (short*)(ws + H1_OFF);
  float* pp1 = (float*)(ws + PP1_OFF);
  float* pp2 = (float*)(ws + PP2_OFF);
  float* ss1 = (float*)(ws + SS1_OFF);
  float* ss2 = (float*)(ws + SS2_OFF);
  float* outp = (float*)d_out;

  convw_kernel<<<512, 256, 0, stream>>>(W0, W1, W0b, W1b);
  topk_kernel<<<B_ * (N_ / 256), 256, 0, stream>>>(xyz1, xyz2, relw, relb, idx, wts);
  build_h_kernel<<<M_, 256, 0, stream>>>(pts1, pts2, idx, wts, h);

  gemm_bt_kernel<K2D_><<<dim3(M_ / 128, C0_ / 128), 256, 0, stream>>>(h, W0b, b0, a1, C0_);

  stats_partial_kernel<<<M_ / 256, C0_, 0, stream>>>(a1, pp1, C0_, 256);
  stats_final_kernel<<<1, 256, 0, stream>>>(pp1, M_ / 256, C0_, g0, be0, ss1);
  norm1_kernel<<<M_, 256, 0, stream>>>(a1, ss1, h1);

  gemm_bt_kernel<C0_><<<dim3(M_ / 128, C1_ / 128), 256, 0, stream>>>(h1, W1b, b1, outp, C1_);

  stats_partial_kernel<<<M_ / 256, C1_, 0, stream>>>(outp, pp2, C1_, 256);
  stats_final_kernel<<<1, 256, 0, stream>>>(pp2, M_ / 256, C1_, g1, be1, ss2);
  norm2_kernel<<<(size_t)M_ * C1_ / 256, 256, 0, stream>>>(outp, ss2);
}

// Round 2
// 559.586 us; speedup vs baseline: 1.2365x; 1.2365x over previous
//
#include <hip/hip_runtime.h>
#include <stdint.h>
#include <stddef.h>

// Problem constants
#define B_   8
#define N_   8192
#define S_   2048
#define D_   256
#define M_   (B_*N_)     // 65536 total points
#define C0_  256         // MLP[0]
#define C1_  128         // MLP[1]
#define K2D_ 512         // 2*D
#define TQ_  64          // queries per topk block
#define TS_  4           // S-segments per topk block
#define SEG_ (S_/TS_)    // 512

typedef __attribute__((ext_vector_type(8))) short short8;
typedef __attribute__((ext_vector_type(4))) short short4v;
typedef __attribute__((ext_vector_type(4))) float f32x4;

__device__ __forceinline__ short f2bf(float f) {
  unsigned u = __float_as_uint(f);
  u += 0x7fffu + ((u >> 16) & 1u);   // round-to-nearest-even
  return (short)(u >> 16);
}

__device__ __forceinline__ void cp16(const void* g, void* l) {
  __builtin_amdgcn_global_load_lds(
      (__attribute__((address_space(1))) void*)(g),
      (__attribute__((address_space(3))) void*)(l), 16, 0, 0);
}

// ---------------------------------------------------------------------------
// K0: convert W0 / W1 to bf16
// ---------------------------------------------------------------------------
__global__ void convw_kernel(const float* __restrict__ W0,
                             const float* __restrict__ W1,
                             short* __restrict__ W0b, short* __restrict__ W1b) {
  int i = blockIdx.x * 256 + threadIdx.x;
  if (i < C0_ * K2D_) W0b[i] = f2bf(W0[i]);
  if (i < C1_ * C0_)  W1b[i] = f2bf(W1[i]);
}

// ---------------------------------------------------------------------------
// K1: top-3 NN + sigmoid relation weights. S split 4-way per block:
// block = 64 queries x 4 segment-threads; per-segment top-3 then ordered merge
// (reproduces sequential strict-< scan bit-exactly, incl. tie-breaks).
// ---------------------------------------------------------------------------
__global__ __launch_bounds__(256, 1)
void topk_kernel(const float* __restrict__ xyz1, const float* __restrict__ xyz2,
                 const float* __restrict__ relw, const float* __restrict__ relb,
                 int* __restrict__ idx_out, float* __restrict__ w_out) {
  __shared__ float4 s2[S_];            // 32 KB: x,y,z,sumsq
  __shared__ float  cd[TS_][TQ_][3];   // 3 KB
  __shared__ int    ci[TS_][TQ_][3];   // 3 KB
  const int tid = threadIdx.x;
  const int b   = blockIdx.x >> 7;            // 128 blocks per batch
  const int q   = tid & 63;
  const int seg = tid >> 6;
  const int n   = (blockIdx.x & 127) * TQ_ + q;

  for (int s = tid; s < S_; s += 256) {
    float x = xyz2[((size_t)b * S_ + s) * 3 + 0];
    float y = xyz2[((size_t)b * S_ + s) * 3 + 1];
    float z = xyz2[((size_t)b * S_ + s) * 3 + 2];
    float ss = __fadd_rn(__fadd_rn(__fmul_rn(x, x), __fmul_rn(y, y)), __fmul_rn(z, z));
    s2[s] = make_float4(x, y, z, ss);
  }
  __syncthreads();

  const float* p = xyz1 + ((size_t)b * N_ + n) * 3;
  const float ax = p[0], ay = p[1], az = p[2];
  const float s1 = __fadd_rn(__fadd_rn(__fmul_rn(ax, ax), __fmul_rn(ay, ay)), __fmul_rn(az, az));

  float d0 = 3.4e38f, d1 = 3.4e38f, d2 = 3.4e38f;
  int   i0 = 0, i1 = 0, i2 = 0;
  const int sbeg = seg * SEG_;
  #pragma unroll 4
  for (int j = 0; j < SEG_; j++) {
    const int s = sbeg + j;
    float4 qv = s2[s];
    float dot = __fadd_rn(__fadd_rn(__fmul_rn(ax, qv.x), __fmul_rn(ay, qv.y)), __fmul_rn(az, qv.z));
    float d = __fsub_rn(__fadd_rn(s1, qv.w), __fmul_rn(2.0f, dot));
    if (d < d2) {
      if (d < d1) {
        d2 = d1; i2 = i1;
        if (d < d0) { d1 = d0; i1 = i0; d0 = d; i0 = s; }
        else        { d1 = d;  i1 = s; }
      } else { d2 = d; i2 = s; }
    }
  }
  cd[seg][q][0] = d0; cd[seg][q][1] = d1; cd[seg][q][2] = d2;
  ci[seg][q][0] = i0; ci[seg][q][1] = i1; ci[seg][q][2] = i2;
  __syncthreads();

  if (tid < TQ_) {
    float m0 = 3.4e38f, m1 = 3.4e38f, m2 = 3.4e38f;
    int   j0 = 0, j1 = 0, j2 = 0;
    #pragma unroll
    for (int sg = 0; sg < TS_; sg++) {
      #pragma unroll
      for (int k = 0; k < 3; k++) {
        float d = cd[sg][q][k];
        int   ix = ci[sg][q][k];
        if (d < m2) {
          if (d < m1) {
            m2 = m1; j2 = j1;
            if (d < m0) { m1 = m0; j1 = j0; m0 = d; j0 = ix; }
            else        { m1 = d;  j1 = ix; }
          } else { m2 = d; j2 = ix; }
        }
      }
    }
    const float w0r = relw[0], w1r = relw[1], w2r = relw[2], w3r = relw[3], br = relb[0];
    const size_t base = ((size_t)b * N_ + n) * 3;
    float dd[3] = {m0, m1, m2};
    int   ii[3] = {j0, j1, j2};
    #pragma unroll
    for (int k = 0; k < 3; k++) {
      float4 qv = s2[ii[k]];
      float ox = ax - qv.x, oy = ay - qv.y, oz = az - qv.z;
      float t = dd[k] * w0r + ox * w1r + oy * w2r + oz * w3r + br;
      float w = 1.0f / (1.0f + expf(-t));
      idx_out[base + k] = ii[k];
      w_out[base + k] = w * (1.0f / 3.0f);
    }
  }
}

// ---------------------------------------------------------------------------
// K2: build h = [points1 | sum_k w_k*points2[idx_k]] as bf16, [M][512]
// 4 rows per block, 64 lanes x float4 per row; 8B bf16x4 stores.
// ---------------------------------------------------------------------------
__global__ __launch_bounds__(256, 1)
void build_h_kernel(const float* __restrict__ p1, const float* __restrict__ p2,
                    const int* __restrict__ idx, const float* __restrict__ wts,
                    short* __restrict__ h) {
  const int tid = threadIdx.x;
  const int row = blockIdx.x * 4 + (tid >> 6);
  const int cl = (tid & 63) * 4;
  const int b = row >> 13;   // /8192
  const int i0 = idx[row * 3 + 0], i1 = idx[row * 3 + 1], i2 = idx[row * 3 + 2];
  const float w0 = wts[row * 3 + 0], w1 = wts[row * 3 + 1], w2 = wts[row * 3 + 2];
  const float* pb = p2 + (size_t)b * S_ * D_;
  float4 a  = *(const float4*)(p1 + (size_t)row * D_ + cl);
  float4 v0 = *(const float4*)(pb + (size_t)i0 * D_ + cl);
  float4 v1 = *(const float4*)(pb + (size_t)i1 * D_ + cl);
  float4 v2 = *(const float4*)(pb + (size_t)i2 * D_ + cl);
  short4v o1 = { f2bf(a.x), f2bf(a.y), f2bf(a.z), f2bf(a.w) };
  short4v o2 = { f2bf(w0 * v0.x + w1 * v1.x + w2 * v2.x),
                 f2bf(w0 * v0.y + w1 * v1.y + w2 * v2.y),
                 f2bf(w0 * v0.z + w1 * v1.z + w2 * v2.z),
                 f2bf(w0 * v0.w + w1 * v1.w + w2 * v2.w) };
  *(short4v*)(h + (size_t)row * K2D_ + cl)       = o1;
  *(short4v*)(h + (size_t)row * K2D_ + D_ + cl)  = o2;
}

// ---------------------------------------------------------------------------
// GEMM: C[M][Nout] = A[M][KTOT](bf16) @ Bw[Nout][KTOT]^T(bf16) + bias
// 128x128 tile per block, 4 waves (2x2), each wave 64x64 via 4x4 MFMA frags.
// ---------------------------------------------------------------------------
template <int KTOT>
__global__ __launch_bounds__(256, 1)
void gemm_bt_kernel(const short* __restrict__ A, const short* __restrict__ Bw,
                    const float* __restrict__ bias, float* __restrict__ C,
                    const int Nout) {
  __shared__ __align__(16) short sA[128 * 32];
  __shared__ __align__(16) short sB[128 * 32];
  const int tid = threadIdx.x;
  const int lane = tid & 63;
  const int wave = tid >> 6;
  const int wm = wave & 1;
  const int wn = wave >> 1;
  const size_t mbase = (size_t)blockIdx.x * 128;
  const int nbase = blockIdx.y * 128;

  const int lrow = lane >> 2;          // 0..15
  const int lcol = (lane & 3) * 8;     // 0,8,16,24

  f32x4 acc[4][4] = {};

  for (int k0 = 0; k0 < KTOT; k0 += 32) {
    #pragma unroll
    for (int t = 0; t < 2; t++) {
      const int r = wave * 32 + t * 16;
      cp16(A  + (mbase + r + lrow) * KTOT + k0 + lcol, &sA[r * 32]);
      cp16(Bw + (size_t)(nbase + r + lrow) * KTOT + k0 + lcol, &sB[r * 32]);
    }
    __syncthreads();

    const int mr = lane & 15;
    const int ks = (lane >> 4) * 8;
    short8 af[4], bfr[4];
    #pragma unroll
    for (int i = 0; i < 4; i++) af[i]  = *(const short8*)&sA[(wm * 64 + i * 16 + mr) * 32 + ks];
    #pragma unroll
    for (int j = 0; j < 4; j++) bfr[j] = *(const short8*)&sB[(wn * 64 + j * 16 + mr) * 32 + ks];
    #pragma unroll
    for (int i = 0; i < 4; i++)
      #pragma unroll
      for (int j = 0; j < 4; j++)
        acc[i][j] = __builtin_amdgcn_mfma_f32_16x16x32_bf16(af[i], bfr[j], acc[i][j], 0, 0, 0);
    __syncthreads();
  }

  const int cr = (lane >> 4) * 4;
  const int cc = lane & 15;
  #pragma unroll
  for (int i = 0; i < 4; i++) {
    #pragma unroll
    for (int j = 0; j < 4; j++) {
      const int col = nbase + wn * 64 + j * 16 + cc;
      const float bv = bias[col];
      #pragma unroll
      for (int r = 0; r < 4; r++) {
        const size_t row = mbase + wm * 64 + i * 16 + cr + r;
        C[row * Nout + col] = acc[i][j][r] + bv;
      }
    }
  }
}

// ---------------------------------------------------------------------------
// Stats: per-channel partial sums over 256-row chunks (deterministic)
// ---------------------------------------------------------------------------
__global__ void stats_partial_kernel(const float* __restrict__ a, float* __restrict__ pp,
                                     const int C, const int rows_per_block) {
  const int c = threadIdx.x;     // blockDim.x == C
  const size_t r0 = (size_t)blockIdx.x * rows_per_block;
  float s = 0.f, s2 = 0.f;
  for (int r = 0; r < rows_per_block; r++) {
    float v = a[(r0 + r) * C + c];
    s += v; s2 += v * v;
  }
  pp[(size_t)blockIdx.x * 2 * C + c]     = s;
  pp[(size_t)blockIdx.x * 2 * C + C + c] = s2;
}

__global__ void stats_final_kernel(const float* __restrict__ pp, const int nparts, const int C,
                                   const float* __restrict__ g, const float* __restrict__ be,
                                   float* __restrict__ ss) {
  const int c = threadIdx.x;
  if (c >= C) return;
  float s = 0.f, s2 = 0.f;
  for (int p = 0; p < nparts; p++) {
    s  += pp[(size_t)p * 2 * C + c];
    s2 += pp[(size_t)p * 2 * C + C + c];
  }
  const float inv = 1.0f / (float)M_;
  float mean = s * inv;
  float var = s2 * inv - mean * mean;
  float sc = g[c] * rsqrtf(var + 1e-5f);
  ss[c] = sc;
  ss[C + c] = be[c] - mean * sc;
}

// ---------------------------------------------------------------------------
// Normalize + ReLU
// ---------------------------------------------------------------------------
__global__ void norm1_kernel(const float* __restrict__ a, const float* __restrict__ ss,
                             short* __restrict__ h1) {
  const size_t i = (size_t)blockIdx.x * 256 + threadIdx.x;
  const int c = threadIdx.x;   // C0_ == 256 == blockDim
  float v = a[i] * ss[c] + ss[C0_ + c];
  v = v > 0.f ? v : 0.f;
  h1[i] = f2bf(v);
}

__global__ void norm2_kernel(float* __restrict__ out, const float* __restrict__ ss) {
  const size_t i = (size_t)blockIdx.x * 256 + threadIdx.x;
  const int c = (int)(i & (C1_ - 1));
  float v = out[i] * ss[c] + ss[C1_ + c];
  out[i] = v > 0.f ? v : 0.f;
}

// ---------------------------------------------------------------------------
// Launch
// ---------------------------------------------------------------------------
extern "C" void kernel_launch(void* const* d_in, const int* in_sizes, int n_in,
                              void* d_out, int out_size, void* d_ws, size_t ws_size,
                              hipStream_t stream) {
  const float* xyz1 = (const float*)d_in[0];
  const float* xyz2 = (const float*)d_in[1];
  const float* pts1 = (const float*)d_in[2];
  const float* pts2 = (const float*)d_in[3];
  const float* relw = (const float*)d_in[4];
  const float* relb = (const float*)d_in[5];
  const float* W0   = (const float*)d_in[6];
  const float* b0   = (const float*)d_in[7];
  const float* g0   = (const float*)d_in[8];
  const float* be0  = (const float*)d_in[9];
  const float* W1   = (const float*)d_in[10];
  const float* b1   = (const float*)d_in[11];
  const float* g1   = (const float*)d_in[12];
  const float* be1  = (const float*)d_in[13];

  char* ws = (char*)d_ws;
  constexpr size_t IDX_OFF = 0;                                    // 65536*3 int
  constexpr size_t WTS_OFF = IDX_OFF + (size_t)M_ * 3 * 4;         // 65536*3 f32
  constexpr size_t W0B_OFF = WTS_OFF + (size_t)M_ * 3 * 4;         // 256*512 bf16
  constexpr size_t W1B_OFF = W0B_OFF + (size_t)C0_ * K2D_ * 2;     // 128*256 bf16
  constexpr size_t H_OFF   = W1B_OFF + (size_t)C1_ * C0_ * 2;      // M*512 bf16
  constexpr size_t A1_OFF  = H_OFF + (size_t)M_ * K2D_ * 2;        // M*256 f32
  constexpr size_t H1_OFF  = A1_OFF + (size_t)M_ * C0_ * 4;        // M*256 bf16
  constexpr size_t PP1_OFF = H1_OFF + (size_t)M_ * C0_ * 2;        // 256*2*256 f32
  constexpr size_t PP2_OFF = PP1_OFF + (size_t)256 * 2 * C0_ * 4;  // 256*2*128 f32
  constexpr size_t SS1_OFF = PP2_OFF + (size_t)256 * 2 * C1_ * 4;  // 2*256 f32
  constexpr size_t SS2_OFF = SS1_OFF + (size_t)2 * C0_ * 4;        // 2*128 f32

  int*   idx = (int*)(ws + IDX_OFF);
  float* wts = (float*)(ws + WTS_OFF);
  short* W0b = (short*)(ws + W0B_OFF);
  short* W1b = (short*)(ws + W1B_OFF);
  short* h   = (short*)(ws + H_OFF);
  float* a1  = (float*)(ws + A1_OFF);
  short* h1  = (short*)(ws + H1_OFF);
  float* pp1 = (float*)(ws + PP1_OFF);
  float* pp2 = (float*)(ws + PP2_OFF);
  float* ss1 = (float*)(ws + SS1_OFF);
  float* ss2 = (float*)(ws + SS2_OFF);
  float* outp = (float*)d_out;

  convw_kernel<<<512, 256, 0, stream>>>(W0, W1, W0b, W1b);
  topk_kernel<<<B_ * (N_ / TQ_), 256, 0, stream>>>(xyz1, xyz2, relw, relb, idx, wts);
  build_h_kernel<<<M_ / 4, 256, 0, stream>>>(pts1, pts2, idx, wts, h);

  gemm_bt_kernel<K2D_><<<dim3(M_ / 128, C0_ / 128), 256, 0, stream>>>(h, W0b, b0, a1, C0_);

  stats_partial_kernel<<<M_ / 256, C0_, 0, stream>>>(a1, pp1, C0_, 256);
  stats_final_kernel<<<1, 256, 0, stream>>>(pp1, M_ / 256, C0_, g0, be0, ss1);
  norm1_kernel<<<M_, 256, 0, stream>>>(a1, ss1, h1);

  gemm_bt_kernel<C0_><<<dim3(M_ / 128, C1_ / 128), 256, 0, stream>>>(h1, W1b, b1, outp, C1_);

  stats_partial_kernel<<<M_ / 256, C1_, 0, stream>>>(outp, pp2, C1_, 256);
  stats_final_kernel<<<1, 256, 0, stream>>>(pp2, M_ / 256, C1_, g1, be1, ss2);
  norm2_kernel<<<(size_t)M_ * C1_ / 256, 256, 0, stream>>>(outp, ss2);
}

// Round 3
// 350.683 us; speedup vs baseline: 1.9731x; 1.5957x over previous
//
#include <hip/hip_runtime.h>
#include <stdint.h>
#include <stddef.h>

// Problem constants
#define B_   8
#define N_   8192
#define S_   2048
#define D_   256
#define M_   (B_*N_)     // 65536 total points
#define C0_  256         // MLP[0]
#define C1_  128         // MLP[1]
#define K2D_ 512         // 2*D
#define TS_  4           // S-segments per topk block
#define SEG_ (S_/TS_)    // 512
#define TQB_ 128         // queries per topk block (2 per lane)

typedef __attribute__((ext_vector_type(8))) short short8;
typedef __attribute__((ext_vector_type(4))) short short4v;
typedef __attribute__((ext_vector_type(4))) float f32x4;

__device__ __forceinline__ short f2bf(float f) {
  unsigned u = __float_as_uint(f);
  u += 0x7fffu + ((u >> 16) & 1u);   // round-to-nearest-even
  return (short)(u >> 16);
}
__device__ __forceinline__ float bf2f(short s) {
  return __uint_as_float(((unsigned)(unsigned short)s) << 16);
}

__device__ __forceinline__ void cp16(const void* g, void* l) {
  __builtin_amdgcn_global_load_lds(
      (__attribute__((address_space(1))) void*)(g),
      (__attribute__((address_space(3))) void*)(l), 16, 0, 0);
}

// ---------------------------------------------------------------------------
// K0: convert W0 / W1 to bf16; block 0 also zeroes the 768-float stats buffer
// (ws is re-poisoned before every call, so this must run every call).
// ---------------------------------------------------------------------------
__global__ void convw_kernel(const float* __restrict__ W0,
                             const float* __restrict__ W1,
                             short* __restrict__ W0b, short* __restrict__ W1b,
                             float* __restrict__ stats) {
  int i = blockIdx.x * 256 + threadIdx.x;
  if (blockIdx.x == 0) {
    stats[threadIdx.x] = 0.f;
    stats[256 + threadIdx.x] = 0.f;
    stats[512 + threadIdx.x] = 0.f;
  }
  if (i < C0_ * K2D_) W0b[i] = f2bf(W0[i]);
  if (i < C1_ * C0_)  W1b[i] = f2bf(W1[i]);
}

// ---------------------------------------------------------------------------
// K1: top-3 NN + sigmoid relation weights.
// Block = 4 waves (one S-segment each); each lane owns 2 queries (128/block).
// Per-pair arithmetic is the exact numpy expression tree (no FMA contraction);
// segment-ordered merge reproduces the sequential strict-< scan bit-exactly.
// ---------------------------------------------------------------------------
__global__ __launch_bounds__(256, 1)
void topk_kernel(const float* __restrict__ xyz1, const float* __restrict__ xyz2,
                 const float* __restrict__ relw, const float* __restrict__ relb,
                 int* __restrict__ idx_out, float* __restrict__ w_out) {
  __shared__ float4 s2[S_];             // 32 KB: x,y,z,sumsq
  __shared__ float  cd[TS_][TQB_][3];   // 6 KB
  __shared__ int    ci[TS_][TQB_][3];   // 6 KB
  const int tid  = threadIdx.x;
  const int lane = tid & 63;
  const int seg  = tid >> 6;
  const int b    = blockIdx.x >> 6;             // 64 blocks per batch
  const int qb   = (blockIdx.x & 63) * TQB_;

  for (int s = tid; s < S_; s += 256) {
    float x = xyz2[((size_t)b * S_ + s) * 3 + 0];
    float y = xyz2[((size_t)b * S_ + s) * 3 + 1];
    float z = xyz2[((size_t)b * S_ + s) * 3 + 2];
    float ss = __fadd_rn(__fadd_rn(__fmul_rn(x, x), __fmul_rn(y, y)), __fmul_rn(z, z));
    s2[s] = make_float4(x, y, z, ss);
  }
  __syncthreads();

  const int qa = 2 * lane, qcb = 2 * lane + 1;
  const float* pa = xyz1 + ((size_t)b * N_ + qb + qa) * 3;
  const float ax0 = pa[0], ay0 = pa[1], az0 = pa[2];
  const float ax1 = pa[3], ay1 = pa[4], az1 = pa[5];
  const float s10 = __fadd_rn(__fadd_rn(__fmul_rn(ax0, ax0), __fmul_rn(ay0, ay0)), __fmul_rn(az0, az0));
  const float s11 = __fadd_rn(__fadd_rn(__fmul_rn(ax1, ax1), __fmul_rn(ay1, ay1)), __fmul_rn(az1, az1));

  float d0a = 3.4e38f, d1a = 3.4e38f, d2a = 3.4e38f;
  int   i0a = 0, i1a = 0, i2a = 0;
  float d0b = 3.4e38f, d1b = 3.4e38f, d2b = 3.4e38f;
  int   i0b = 0, i1b = 0, i2b = 0;
  const int sbeg = seg * SEG_;
  #pragma unroll 2
  for (int j = 0; j < SEG_; j++) {
    const int s = sbeg + j;
    float4 qv = s2[s];
    float dot0 = __fadd_rn(__fadd_rn(__fmul_rn(ax0, qv.x), __fmul_rn(ay0, qv.y)), __fmul_rn(az0, qv.z));
    float da = __fsub_rn(__fadd_rn(s10, qv.w), __fmul_rn(2.0f, dot0));
    if (da < d2a) {
      if (da < d1a) {
        d2a = d1a; i2a = i1a;
        if (da < d0a) { d1a = d0a; i1a = i0a; d0a = da; i0a = s; }
        else          { d1a = da;  i1a = s; }
      } else { d2a = da; i2a = s; }
    }
    float dot1 = __fadd_rn(__fadd_rn(__fmul_rn(ax1, qv.x), __fmul_rn(ay1, qv.y)), __fmul_rn(az1, qv.z));
    float db = __fsub_rn(__fadd_rn(s11, qv.w), __fmul_rn(2.0f, dot1));
    if (db < d2b) {
      if (db < d1b) {
        d2b = d1b; i2b = i1b;
        if (db < d0b) { d1b = d0b; i1b = i0b; d0b = db; i0b = s; }
        else          { d1b = db;  i1b = s; }
      } else { d2b = db; i2b = s; }
    }
  }
  cd[seg][qa][0] = d0a; cd[seg][qa][1] = d1a; cd[seg][qa][2] = d2a;
  ci[seg][qa][0] = i0a; ci[seg][qa][1] = i1a; ci[seg][qa][2] = i2a;
  cd[seg][qcb][0] = d0b; cd[seg][qcb][1] = d1b; cd[seg][qcb][2] = d2b;
  ci[seg][qcb][0] = i0b; ci[seg][qcb][1] = i1b; ci[seg][qcb][2] = i2b;
  __syncthreads();

  if (tid < TQB_) {
    const int n = qb + tid;
    float m0 = 3.4e38f, m1 = 3.4e38f, m2 = 3.4e38f;
    int   j0 = 0, j1 = 0, j2 = 0;
    #pragma unroll
    for (int sg = 0; sg < TS_; sg++) {
      #pragma unroll
      for (int k = 0; k < 3; k++) {
        float d = cd[sg][tid][k];
        int   ix = ci[sg][tid][k];
        if (d < m2) {
          if (d < m1) {
            m2 = m1; j2 = j1;
            if (d < m0) { m1 = m0; j1 = j0; m0 = d; j0 = ix; }
            else        { m1 = d;  j1 = ix; }
          } else { m2 = d; j2 = ix; }
        }
      }
    }
    const float* p = xyz1 + ((size_t)b * N_ + n) * 3;
    const float ax = p[0], ay = p[1], az = p[2];
    const float w0r = relw[0], w1r = relw[1], w2r = relw[2], w3r = relw[3], br = relb[0];
    const size_t base = ((size_t)b * N_ + n) * 3;
    float dd[3] = {m0, m1, m2};
    int   ii[3] = {j0, j1, j2};
    #pragma unroll
    for (int k = 0; k < 3; k++) {
      float4 qv = s2[ii[k]];
      float ox = ax - qv.x, oy = ay - qv.y, oz = az - qv.z;
      float t = dd[k] * w0r + ox * w1r + oy * w2r + oz * w3r + br;
      float w = 1.0f / (1.0f + expf(-t));
      idx_out[base + k] = ii[k];
      w_out[base + k] = w * (1.0f / 3.0f);
    }
  }
}

// ---------------------------------------------------------------------------
// K2: build h = [points1 | sum_k w_k*points2[idx_k]] as bf16, [M][512]
// ---------------------------------------------------------------------------
__global__ __launch_bounds__(256, 1)
void build_h_kernel(const float* __restrict__ p1, const float* __restrict__ p2,
                    const int* __restrict__ idx, const float* __restrict__ wts,
                    short* __restrict__ h) {
  const int tid = threadIdx.x;
  const int row = blockIdx.x * 4 + (tid >> 6);
  const int cl = (tid & 63) * 4;
  const int b = row >> 13;   // /8192
  const int i0 = idx[row * 3 + 0], i1 = idx[row * 3 + 1], i2 = idx[row * 3 + 2];
  const float w0 = wts[row * 3 + 0], w1 = wts[row * 3 + 1], w2 = wts[row * 3 + 2];
  const float* pb = p2 + (size_t)b * S_ * D_;
  float4 a  = *(const float4*)(p1 + (size_t)row * D_ + cl);
  float4 v0 = *(const float4*)(pb + (size_t)i0 * D_ + cl);
  float4 v1 = *(const float4*)(pb + (size_t)i1 * D_ + cl);
  float4 v2 = *(const float4*)(pb + (size_t)i2 * D_ + cl);
  short4v o1 = { f2bf(a.x), f2bf(a.y), f2bf(a.z), f2bf(a.w) };
  short4v o2 = { f2bf(w0 * v0.x + w1 * v1.x + w2 * v2.x),
                 f2bf(w0 * v0.y + w1 * v1.y + w2 * v2.y),
                 f2bf(w0 * v0.z + w1 * v1.z + w2 * v2.z),
                 f2bf(w0 * v0.w + w1 * v1.w + w2 * v2.w) };
  *(short4v*)(h + (size_t)row * K2D_ + cl)       = o1;
  *(short4v*)(h + (size_t)row * K2D_ + D_ + cl)  = o2;
}

// ---------------------------------------------------------------------------
// GEMM: Cb[M][Nout](bf16) = A[M][KTOT](bf16) @ Bw[Nout][KTOT]^T(bf16) + bias
// 128x128 tile, 4 waves (2x2), 4x4 MFMA frags/wave. Epilogue also reduces
// per-column (sum, sumsq) over the block's 128 rows (bias EXCLUDED; folded
// analytically in stats_final) and atomicAdds into stats[2*Nout].
// ---------------------------------------------------------------------------
template <int KTOT>
__global__ __launch_bounds__(256, 1)
void gemm_bt_kernel(const short* __restrict__ A, const short* __restrict__ Bw,
                    const float* __restrict__ bias, short* __restrict__ Cb,
                    float* __restrict__ stats, const int Nout) {
  __shared__ __align__(16) short sA[128 * 32];
  __shared__ __align__(16) short sB[128 * 32];
  const int tid = threadIdx.x;
  const int lane = tid & 63;
  const int wave = tid >> 6;
  const int wm = wave & 1;
  const int wn = wave >> 1;
  const size_t mbase = (size_t)blockIdx.x * 128;
  const int nbase = blockIdx.y * 128;

  const int lrow = lane >> 2;          // 0..15
  const int lcol = (lane & 3) * 8;     // 0,8,16,24

  f32x4 acc[4][4] = {};

  for (int k0 = 0; k0 < KTOT; k0 += 32) {
    #pragma unroll
    for (int t = 0; t < 2; t++) {
      const int r = wave * 32 + t * 16;
      cp16(A  + (mbase + r + lrow) * KTOT + k0 + lcol, &sA[r * 32]);
      cp16(Bw + (size_t)(nbase + r + lrow) * KTOT + k0 + lcol, &sB[r * 32]);
    }
    __syncthreads();

    const int mr = lane & 15;
    const int ks = (lane >> 4) * 8;
    short8 af[4], bfr[4];
    #pragma unroll
    for (int i = 0; i < 4; i++) af[i]  = *(const short8*)&sA[(wm * 64 + i * 16 + mr) * 32 + ks];
    #pragma unroll
    for (int j = 0; j < 4; j++) bfr[j] = *(const short8*)&sB[(wn * 64 + j * 16 + mr) * 32 + ks];
    #pragma unroll
    for (int i = 0; i < 4; i++)
      #pragma unroll
      for (int j = 0; j < 4; j++)
        acc[i][j] = __builtin_amdgcn_mfma_f32_16x16x32_bf16(af[i], bfr[j], acc[i][j], 0, 0, 0);
    __syncthreads();
  }

  const int cr = (lane >> 4) * 4;
  const int cc = lane & 15;
  float ps[4], ps2[4];
  #pragma unroll
  for (int j = 0; j < 4; j++) {
    const int col = nbase + wn * 64 + j * 16 + cc;
    const float bv = bias[col];
    float s = 0.f, s2 = 0.f;
    #pragma unroll
    for (int i = 0; i < 4; i++) {
      #pragma unroll
      for (int r = 0; r < 4; r++) {
        const float v = acc[i][j][r];
        s += v; s2 += v * v;
        const size_t row = mbase + wm * 64 + i * 16 + cr + r;
        Cb[row * Nout + col] = f2bf(v + bv);
      }
    }
    ps[j] = s; ps2[j] = s2;
  }
  // reduce the 4 row-groups (lane>>4) of this wave
  #pragma unroll
  for (int j = 0; j < 4; j++) {
    ps[j]  += __shfl_xor(ps[j], 16);  ps[j]  += __shfl_xor(ps[j], 32);
    ps2[j] += __shfl_xor(ps2[j], 16); ps2[j] += __shfl_xor(ps2[j], 32);
  }
  float* sred = (float*)sA;   // reuse LDS: 128 cols x {s,s2}
  if (wm == 1 && lane < 16) {
    #pragma unroll
    for (int j = 0; j < 4; j++) {
      const int c = wn * 64 + j * 16 + lane;
      sred[2 * c] = ps[j]; sred[2 * c + 1] = ps2[j];
    }
  }
  __syncthreads();
  if (wm == 0 && lane < 16) {
    #pragma unroll
    for (int j = 0; j < 4; j++) {
      const int c = wn * 64 + j * 16 + lane;
      atomicAdd(&stats[nbase + c],        ps[j]  + sred[2 * c]);
      atomicAdd(&stats[Nout + nbase + c], ps2[j] + sred[2 * c + 1]);
    }
  }
}

// ---------------------------------------------------------------------------
// stats_final: scale/shift from accumulated (sum, sumsq); bias folded in.
// ---------------------------------------------------------------------------
__global__ void stats_final_kernel(const float* __restrict__ stats, const int C,
                                   const float* __restrict__ bias,
                                   const float* __restrict__ g, const float* __restrict__ be,
                                   float* __restrict__ ss) {
  const int c = threadIdx.x;
  if (c >= C) return;
  const float inv = 1.0f / (float)M_;
  float m0 = stats[c] * inv;                 // mean excluding bias
  float var = stats[C + c] * inv - m0 * m0;  // bias shift cancels in var
  float mean = m0 + bias[c];
  float sc = g[c] * rsqrtf(var + 1e-5f);
  ss[c] = sc;
  ss[C + c] = be[c] - mean * sc;
}

// ---------------------------------------------------------------------------
// norm1: h1 = bf16(relu(a1*sc + sh)), 8 elems/thread
// ---------------------------------------------------------------------------
__global__ __launch_bounds__(256, 1)
void norm1_kernel(const short* __restrict__ a1, const float* __restrict__ ss,
                  short* __restrict__ h1) {
  const size_t t = (size_t)blockIdx.x * 256 + threadIdx.x;
  const size_t base = t * 8;
  const int c = (int)(base & (C0_ - 1));
  short8 v8 = *(const short8*)(a1 + base);
  short8 o;
  #pragma unroll
  for (int k = 0; k < 8; k++) {
    float v = bf2f(v8[k]) * ss[c + k] + ss[C0_ + c + k];
    o[k] = f2bf(v > 0.f ? v : 0.f);
  }
  *(short8*)(h1 + base) = o;
}

// ---------------------------------------------------------------------------
// norm2: out(f32) = relu(a2*sc + sh), 8 elems/thread
// ---------------------------------------------------------------------------
__global__ __launch_bounds__(256, 1)
void norm2_kernel(const short* __restrict__ a2, const float* __restrict__ ss,
                  float* __restrict__ out) {
  const size_t t = (size_t)blockIdx.x * 256 + threadIdx.x;
  const size_t base = t * 8;
  const int c = (int)(base & (C1_ - 1));
  short8 v8 = *(const short8*)(a2 + base);
  float4 o0, o1;
  float vv[8];
  #pragma unroll
  for (int k = 0; k < 8; k++) {
    float v = bf2f(v8[k]) * ss[c + k] + ss[C1_ + c + k];
    vv[k] = v > 0.f ? v : 0.f;
  }
  o0 = make_float4(vv[0], vv[1], vv[2], vv[3]);
  o1 = make_float4(vv[4], vv[5], vv[6], vv[7]);
  *(float4*)(out + base)     = o0;
  *(float4*)(out + base + 4) = o1;
}

// ---------------------------------------------------------------------------
// Launch
// ---------------------------------------------------------------------------
extern "C" void kernel_launch(void* const* d_in, const int* in_sizes, int n_in,
                              void* d_out, int out_size, void* d_ws, size_t ws_size,
                              hipStream_t stream) {
  const float* xyz1 = (const float*)d_in[0];
  const float* xyz2 = (const float*)d_in[1];
  const float* pts1 = (const float*)d_in[2];
  const float* pts2 = (const float*)d_in[3];
  const float* relw = (const float*)d_in[4];
  const float* relb = (const float*)d_in[5];
  const float* W0   = (const float*)d_in[6];
  const float* b0   = (const float*)d_in[7];
  const float* g0   = (const float*)d_in[8];
  const float* be0  = (const float*)d_in[9];
  const float* W1   = (const float*)d_in[10];
  const float* b1   = (const float*)d_in[11];
  const float* g1   = (const float*)d_in[12];
  const float* be1  = (const float*)d_in[13];

  char* ws = (char*)d_ws;
  constexpr size_t IDX_OFF = 0;                                    // M*3 int
  constexpr size_t WTS_OFF = IDX_OFF + (size_t)M_ * 3 * 4;         // M*3 f32
  constexpr size_t W0B_OFF = WTS_OFF + (size_t)M_ * 3 * 4;         // 256*512 bf16
  constexpr size_t W1B_OFF = W0B_OFF + (size_t)C0_ * K2D_ * 2;     // 128*256 bf16
  constexpr size_t H_OFF   = W1B_OFF + (size_t)C1_ * C0_ * 2;      // M*512 bf16
  constexpr size_t A1_OFF  = H_OFF + (size_t)M_ * K2D_ * 2;        // M*256 bf16
  constexpr size_t H1_OFF  = A1_OFF + (size_t)M_ * C0_ * 2;        // M*256 bf16
  constexpr size_t A2_OFF  = H1_OFF + (size_t)M_ * C0_ * 2;        // M*128 bf16
  constexpr size_t ST_OFF  = A2_OFF + (size_t)M_ * C1_ * 2;        // 768 f32 (stats1:512, stats2:256)
  constexpr size_t SS1_OFF = ST_OFF + (size_t)768 * 4;             // 2*256 f32
  constexpr size_t SS2_OFF = SS1_OFF + (size_t)2 * C0_ * 4;        // 2*128 f32

  int*   idx  = (int*)(ws + IDX_OFF);
  float* wts  = (float*)(ws + WTS_OFF);
  short* W0b  = (short*)(ws + W0B_OFF);
  short* W1b  = (short*)(ws + W1B_OFF);
  short* h    = (short*)(ws + H_OFF);
  short* a1   = (short*)(ws + A1_OFF);
  short* h1   = (short*)(ws + H1_OFF);
  short* a2   = (short*)(ws + A2_OFF);
  float* st   = (float*)(ws + ST_OFF);   // stats1 = st, stats2 = st + 512
  float* ss1  = (float*)(ws + SS1_OFF);
  float* ss2  = (float*)(ws + SS2_OFF);
  float* outp = (float*)d_out;

  convw_kernel<<<512, 256, 0, stream>>>(W0, W1, W0b, W1b, st);
  topk_kernel<<<B_ * (N_ / TQB_), 256, 0, stream>>>(xyz1, xyz2, relw, relb, idx, wts);
  build_h_kernel<<<M_ / 4, 256, 0, stream>>>(pts1, pts2, idx, wts, h);

  gemm_bt_kernel<K2D_><<<dim3(M_ / 128, C0_ / 128), 256, 0, stream>>>(h, W0b, b0, a1, st, C0_);
  stats_final_kernel<<<1, 256, 0, stream>>>(st, C0_, b0, g0, be0, ss1);
  norm1_kernel<<<(size_t)M_ * C0_ / 8 / 256, 256, 0, stream>>>(a1, ss1, h1);

  gemm_bt_kernel<C0_><<<dim3(M_ / 128, C1_ / 128), 256, 0, stream>>>(h1, W1b, b1, a2, st + 512, C1_);
  stats_final_kernel<<<1, 128, 0, stream>>>(st + 512, C1_, b1, g1, be1, ss2);
  norm2_kernel<<<(size_t)M_ * C1_ / 8 / 256, 256, 0, stream>>>(a2, ss2, outp);
}

// Round 4
// 320.908 us; speedup vs baseline: 2.1562x; 1.0928x over previous
//
#include <hip/hip_runtime.h>
#include <stdint.h>
#include <stddef.h>

// Problem constants
#define B_   8
#define N_   8192
#define S_   2048
#define D_   256
#define M_   (B_*N_)     // 65536 total points
#define C0_  256         // MLP[0]
#define C1_  128         // MLP[1]
#define K2D_ 512         // 2*D
#define TS_  4           // S-segments per topk block
#define SEG_ (S_/TS_)    // 512

typedef __attribute__((ext_vector_type(8))) short short8;
typedef __attribute__((ext_vector_type(4))) short short4v;
typedef __attribute__((ext_vector_type(4))) float f32x4;
typedef __attribute__((ext_vector_type(2))) float f32x2;

__device__ __forceinline__ short f2bf(float f) {
  unsigned u = __float_as_uint(f);
  u += 0x7fffu + ((u >> 16) & 1u);   // round-to-nearest-even
  return (short)(u >> 16);
}
__device__ __forceinline__ float bf2f(short s) {
  return __uint_as_float(((unsigned)(unsigned short)s) << 16);
}

__device__ __forceinline__ void cp16(const void* g, void* l) {
  __builtin_amdgcn_global_load_lds(
      (__attribute__((address_space(1))) void*)(g),
      (__attribute__((address_space(3))) void*)(l), 16, 0, 0);
}

// ---------------------------------------------------------------------------
// K0: convert W0/W1 to bf16; build component-SoA xyz2p (x|y|z|sumsq streams
// per batch); block 0 zeroes the 768-float stats buffer.
// ---------------------------------------------------------------------------
__global__ void convw_kernel(const float* __restrict__ W0,
                             const float* __restrict__ W1,
                             const float* __restrict__ xyz2,
                             short* __restrict__ W0b, short* __restrict__ W1b,
                             float* __restrict__ xyz2p, float* __restrict__ stats) {
  int i = blockIdx.x * 256 + threadIdx.x;
  if (blockIdx.x == 0) {
    stats[threadIdx.x] = 0.f;
    stats[256 + threadIdx.x] = 0.f;
    stats[512 + threadIdx.x] = 0.f;
  }
  if (i < C0_ * K2D_) W0b[i] = f2bf(W0[i]);
  if (i < C1_ * C0_)  W1b[i] = f2bf(W1[i]);
  if (i < B_ * S_) {
    const int b = i >> 11, s = i & (S_ - 1);
    float x = xyz2[(size_t)i * 3 + 0];
    float y = xyz2[(size_t)i * 3 + 1];
    float z = xyz2[(size_t)i * 3 + 2];
    float ss = __fadd_rn(__fadd_rn(__fmul_rn(x, x), __fmul_rn(y, y)), __fmul_rn(z, z));
    float* xw = xyz2p + (size_t)b * 4 * S_;
    xw[s] = x; xw[S_ + s] = y; xw[2 * S_ + s] = z; xw[3 * S_ + s] = ss;
  }
}

// ---------------------------------------------------------------------------
// K1: top-3 NN + sigmoid relation weights.
// 1024 blocks x 4 waves; wave = one S-segment for 64 queries (1 per lane).
// Candidate feed: wave-uniform global loads from component-SoA (L2-resident),
// packed f32x2 arithmetic (v_pk_*), contract(off) keeps numpy bit-exactness.
// Segment-ordered merge reproduces the sequential strict-< scan exactly.
// ---------------------------------------------------------------------------
__global__ __launch_bounds__(256, 1)
void topk_kernel(const float* __restrict__ xyz1, const float* __restrict__ xyz2p,
                 const float* __restrict__ relw, const float* __restrict__ relb,
                 int* __restrict__ idx_out, float* __restrict__ w_out) {
  __shared__ float cd[TS_][64][3];   // 3 KB
  __shared__ int   ci[TS_][64][3];   // 3 KB
  const int tid  = threadIdx.x;
  const int lane = tid & 63;
  const int seg  = __builtin_amdgcn_readfirstlane(tid >> 6);
  const int b    = blockIdx.x >> 7;             // 128 blocks per batch
  const int n    = (blockIdx.x & 127) * 64 + lane;

  const float* p = xyz1 + ((size_t)b * N_ + n) * 3;
  const float ax = p[0], ay = p[1], az = p[2];
  const float s1 = __fadd_rn(__fadd_rn(__fmul_rn(ax, ax), __fmul_rn(ay, ay)), __fmul_rn(az, az));

  const float* xw = xyz2p + (size_t)b * 4 * S_;
  const f32x2* XP = (const f32x2*)(xw)           + seg * (SEG_ / 2);
  const f32x2* YP = (const f32x2*)(xw + S_)      + seg * (SEG_ / 2);
  const f32x2* ZP = (const f32x2*)(xw + 2 * S_)  + seg * (SEG_ / 2);
  const f32x2* WP = (const f32x2*)(xw + 3 * S_)  + seg * (SEG_ / 2);

  float d0 = 3.4e38f, d1 = 3.4e38f, d2 = 3.4e38f;
  int   i0 = 0, i1 = 0, i2 = 0;
  const int sbeg = seg * SEG_;
  {
    #pragma clang fp contract(off)
    #pragma unroll 4
    for (int pr = 0; pr < SEG_ / 2; pr++) {
      f32x2 X = XP[pr], Y = YP[pr], Z = ZP[pr], W = WP[pr];
      f32x2 t1 = ax * X;
      f32x2 t2 = ay * Y;
      f32x2 t3 = az * Z;
      f32x2 dt = (t1 + t2) + t3;
      f32x2 e  = s1 + W;
      f32x2 m  = 2.0f * dt;
      f32x2 d  = e - m;
      const float dlo = d.x, dhi = d.y;
      if (fminf(dlo, dhi) < d2) {
        const int s = sbeg + 2 * pr;
        if (dlo < d2) {
          if (dlo < d1) {
            d2 = d1; i2 = i1;
            if (dlo < d0) { d1 = d0; i1 = i0; d0 = dlo; i0 = s; }
            else          { d1 = dlo; i1 = s; }
          } else { d2 = dlo; i2 = s; }
        }
        if (dhi < d2) {
          if (dhi < d1) {
            d2 = d1; i2 = i1;
            if (dhi < d0) { d1 = d0; i1 = i0; d0 = dhi; i0 = s + 1; }
            else          { d1 = dhi; i1 = s + 1; }
          } else { d2 = dhi; i2 = s + 1; }
        }
      }
    }
  }
  cd[seg][lane][0] = d0; cd[seg][lane][1] = d1; cd[seg][lane][2] = d2;
  ci[seg][lane][0] = i0; ci[seg][lane][1] = i1; ci[seg][lane][2] = i2;
  __syncthreads();

  if (tid < 64) {
    float m0 = 3.4e38f, m1 = 3.4e38f, m2 = 3.4e38f;
    int   j0 = 0, j1 = 0, j2 = 0;
    #pragma unroll
    for (int sg = 0; sg < TS_; sg++) {
      #pragma unroll
      for (int k = 0; k < 3; k++) {
        float d = cd[sg][tid][k];
        int   ix = ci[sg][tid][k];
        if (d < m2) {
          if (d < m1) {
            m2 = m1; j2 = j1;
            if (d < m0) { m1 = m0; j1 = j0; m0 = d; j0 = ix; }
            else        { m1 = d;  j1 = ix; }
          } else { m2 = d; j2 = ix; }
        }
      }
    }
    const float w0r = relw[0], w1r = relw[1], w2r = relw[2], w3r = relw[3], br = relb[0];
    const size_t base = ((size_t)b * N_ + n) * 3;
    float dd[3] = {m0, m1, m2};
    int   ii[3] = {j0, j1, j2};
    #pragma unroll
    for (int k = 0; k < 3; k++) {
      const int s = ii[k];
      float ox = ax - xw[s], oy = ay - xw[S_ + s], oz = az - xw[2 * S_ + s];
      float t = dd[k] * w0r + ox * w1r + oy * w2r + oz * w3r + br;
      float w = 1.0f / (1.0f + expf(-t));
      idx_out[base + k] = s;
      w_out[base + k] = w * (1.0f / 3.0f);
    }
  }
}

// ---------------------------------------------------------------------------
// K2: build h = [points1 | sum_k w_k*points2[idx_k]] as bf16, [M][512]
// ---------------------------------------------------------------------------
__global__ __launch_bounds__(256, 1)
void build_h_kernel(const float* __restrict__ p1, const float* __restrict__ p2,
                    const int* __restrict__ idx, const float* __restrict__ wts,
                    short* __restrict__ h) {
  const int tid = threadIdx.x;
  const int row = blockIdx.x * 4 + (tid >> 6);
  const int cl = (tid & 63) * 4;
  const int b = row >> 13;   // /8192
  const int i0 = idx[row * 3 + 0], i1 = idx[row * 3 + 1], i2 = idx[row * 3 + 2];
  const float w0 = wts[row * 3 + 0], w1 = wts[row * 3 + 1], w2 = wts[row * 3 + 2];
  const float* pb = p2 + (size_t)b * S_ * D_;
  float4 a  = *(const float4*)(p1 + (size_t)row * D_ + cl);
  float4 v0 = *(const float4*)(pb + (size_t)i0 * D_ + cl);
  float4 v1 = *(const float4*)(pb + (size_t)i1 * D_ + cl);
  float4 v2 = *(const float4*)(pb + (size_t)i2 * D_ + cl);
  short4v o1 = { f2bf(a.x), f2bf(a.y), f2bf(a.z), f2bf(a.w) };
  short4v o2 = { f2bf(w0 * v0.x + w1 * v1.x + w2 * v2.x),
                 f2bf(w0 * v0.y + w1 * v1.y + w2 * v2.y),
                 f2bf(w0 * v0.z + w1 * v1.z + w2 * v2.z),
                 f2bf(w0 * v0.w + w1 * v1.w + w2 * v2.w) };
  *(short4v*)(h + (size_t)row * K2D_ + cl)       = o1;
  *(short4v*)(h + (size_t)row * K2D_ + D_ + cl)  = o2;
}

// ---------------------------------------------------------------------------
// GEMM: Cb[M][Nout](bf16) = A[M][KTOT](bf16) @ Bw[Nout][KTOT]^T(bf16) + bias
// 128x128 tile, 4 waves (2x2), 4x4 MFMA frags/wave. Epilogue reduces
// per-column (sum, sumsq) over the block's 128 rows (bias excluded; folded
// analytically in stats_final) and atomicAdds into stats[2*Nout].
// ---------------------------------------------------------------------------
template <int KTOT>
__global__ __launch_bounds__(256, 1)
void gemm_bt_kernel(const short* __restrict__ A, const short* __restrict__ Bw,
                    const float* __restrict__ bias, short* __restrict__ Cb,
                    float* __restrict__ stats, const int Nout) {
  __shared__ __align__(16) short sA[128 * 32];
  __shared__ __align__(16) short sB[128 * 32];
  const int tid = threadIdx.x;
  const int lane = tid & 63;
  const int wave = tid >> 6;
  const int wm = wave & 1;
  const int wn = wave >> 1;
  const size_t mbase = (size_t)blockIdx.x * 128;
  const int nbase = blockIdx.y * 128;

  const int lrow = lane >> 2;          // 0..15
  const int lcol = (lane & 3) * 8;     // 0,8,16,24

  f32x4 acc[4][4] = {};

  for (int k0 = 0; k0 < KTOT; k0 += 32) {
    #pragma unroll
    for (int t = 0; t < 2; t++) {
      const int r = wave * 32 + t * 16;
      cp16(A  + (mbase + r + lrow) * KTOT + k0 + lcol, &sA[r * 32]);
      cp16(Bw + (size_t)(nbase + r + lrow) * KTOT + k0 + lcol, &sB[r * 32]);
    }
    __syncthreads();

    const int mr = lane & 15;
    const int ks = (lane >> 4) * 8;
    short8 af[4], bfr[4];
    #pragma unroll
    for (int i = 0; i < 4; i++) af[i]  = *(const short8*)&sA[(wm * 64 + i * 16 + mr) * 32 + ks];
    #pragma unroll
    for (int j = 0; j < 4; j++) bfr[j] = *(const short8*)&sB[(wn * 64 + j * 16 + mr) * 32 + ks];
    #pragma unroll
    for (int i = 0; i < 4; i++)
      #pragma unroll
      for (int j = 0; j < 4; j++)
        acc[i][j] = __builtin_amdgcn_mfma_f32_16x16x32_bf16(af[i], bfr[j], acc[i][j], 0, 0, 0);
    __syncthreads();
  }

  const int cr = (lane >> 4) * 4;
  const int cc = lane & 15;
  float ps[4], ps2[4];
  #pragma unroll
  for (int j = 0; j < 4; j++) {
    const int col = nbase + wn * 64 + j * 16 + cc;
    const float bv = bias[col];
    float s = 0.f, s2 = 0.f;
    #pragma unroll
    for (int i = 0; i < 4; i++) {
      #pragma unroll
      for (int r = 0; r < 4; r++) {
        const float v = acc[i][j][r];
        s += v; s2 += v * v;
        const size_t row = mbase + wm * 64 + i * 16 + cr + r;
        Cb[row * Nout + col] = f2bf(v + bv);
      }
    }
    ps[j] = s; ps2[j] = s2;
  }
  #pragma unroll
  for (int j = 0; j < 4; j++) {
    ps[j]  += __shfl_xor(ps[j], 16);  ps[j]  += __shfl_xor(ps[j], 32);
    ps2[j] += __shfl_xor(ps2[j], 16); ps2[j] += __shfl_xor(ps2[j], 32);
  }
  float* sred = (float*)sA;   // reuse LDS: 128 cols x {s,s2}
  if (wm == 1 && lane < 16) {
    #pragma unroll
    for (int j = 0; j < 4; j++) {
      const int c = wn * 64 + j * 16 + lane;
      sred[2 * c] = ps[j]; sred[2 * c + 1] = ps2[j];
    }
  }
  __syncthreads();
  if (wm == 0 && lane < 16) {
    #pragma unroll
    for (int j = 0; j < 4; j++) {
      const int c = wn * 64 + j * 16 + lane;
      atomicAdd(&stats[nbase + c],        ps[j]  + sred[2 * c]);
      atomicAdd(&stats[Nout + nbase + c], ps2[j] + sred[2 * c + 1]);
    }
  }
}

// ---------------------------------------------------------------------------
// stats_final: scale/shift from accumulated (sum, sumsq); bias folded in.
// ---------------------------------------------------------------------------
__global__ void stats_final_kernel(const float* __restrict__ stats, const int C,
                                   const float* __restrict__ bias,
                                   const float* __restrict__ g, const float* __restrict__ be,
                                   float* __restrict__ ss) {
  const int c = threadIdx.x;
  if (c >= C) return;
  const float inv = 1.0f / (float)M_;
  float m0 = stats[c] * inv;                 // mean excluding bias
  float var = stats[C + c] * inv - m0 * m0;  // bias shift cancels in var
  float mean = m0 + bias[c];
  float sc = g[c] * rsqrtf(var + 1e-5f);
  ss[c] = sc;
  ss[C + c] = be[c] - mean * sc;
}

// ---------------------------------------------------------------------------
// norm1: h1 = bf16(relu(a1*sc + sh)), 8 elems/thread
// ---------------------------------------------------------------------------
__global__ __launch_bounds__(256, 1)
void norm1_kernel(const short* __restrict__ a1, const float* __restrict__ ss,
                  short* __restrict__ h1) {
  const size_t t = (size_t)blockIdx.x * 256 + threadIdx.x;
  const size_t base = t * 8;
  const int c = (int)(base & (C0_ - 1));
  short8 v8 = *(const short8*)(a1 + base);
  short8 o;
  #pragma unroll
  for (int k = 0; k < 8; k++) {
    float v = bf2f(v8[k]) * ss[c + k] + ss[C0_ + c + k];
    o[k] = f2bf(v > 0.f ? v : 0.f);
  }
  *(short8*)(h1 + base) = o;
}

// ---------------------------------------------------------------------------
// norm2: out(f32) = relu(a2*sc + sh), 8 elems/thread
// ---------------------------------------------------------------------------
__global__ __launch_bounds__(256, 1)
void norm2_kernel(const short* __restrict__ a2, const float* __restrict__ ss,
                  float* __restrict__ out) {
  const size_t t = (size_t)blockIdx.x * 256 + threadIdx.x;
  const size_t base = t * 8;
  const int c = (int)(base & (C1_ - 1));
  short8 v8 = *(const short8*)(a2 + base);
  float vv[8];
  #pragma unroll
  for (int k = 0; k < 8; k++) {
    float v = bf2f(v8[k]) * ss[c + k] + ss[C1_ + c + k];
    vv[k] = v > 0.f ? v : 0.f;
  }
  *(float4*)(out + base)     = make_float4(vv[0], vv[1], vv[2], vv[3]);
  *(float4*)(out + base + 4) = make_float4(vv[4], vv[5], vv[6], vv[7]);
}

// ---------------------------------------------------------------------------
// Launch
// ---------------------------------------------------------------------------
extern "C" void kernel_launch(void* const* d_in, const int* in_sizes, int n_in,
                              void* d_out, int out_size, void* d_ws, size_t ws_size,
                              hipStream_t stream) {
  const float* xyz1 = (const float*)d_in[0];
  const float* xyz2 = (const float*)d_in[1];
  const float* pts1 = (const float*)d_in[2];
  const float* pts2 = (const float*)d_in[3];
  const float* relw = (const float*)d_in[4];
  const float* relb = (const float*)d_in[5];
  const float* W0   = (const float*)d_in[6];
  const float* b0   = (const float*)d_in[7];
  const float* g0   = (const float*)d_in[8];
  const float* be0  = (const float*)d_in[9];
  const float* W1   = (const float*)d_in[10];
  const float* b1   = (const float*)d_in[11];
  const float* g1   = (const float*)d_in[12];
  const float* be1  = (const float*)d_in[13];

  char* ws = (char*)d_ws;
  constexpr size_t IDX_OFF = 0;                                    // M*3 int
  constexpr size_t WTS_OFF = IDX_OFF + (size_t)M_ * 3 * 4;         // M*3 f32
  constexpr size_t W0B_OFF = WTS_OFF + (size_t)M_ * 3 * 4;         // 256*512 bf16
  constexpr size_t W1B_OFF = W0B_OFF + (size_t)C0_ * K2D_ * 2;     // 128*256 bf16
  constexpr size_t XW_OFF  = W1B_OFF + (size_t)C1_ * C0_ * 2;      // B*4*S f32
  constexpr size_t H_OFF   = XW_OFF + (size_t)B_ * 4 * S_ * 4;     // M*512 bf16
  constexpr size_t A1_OFF  = H_OFF + (size_t)M_ * K2D_ * 2;        // M*256 bf16
  constexpr size_t H1_OFF  = A1_OFF + (size_t)M_ * C0_ * 2;        // M*256 bf16
  constexpr size_t A2_OFF  = H1_OFF + (size_t)M_ * C0_ * 2;        // M*128 bf16
  constexpr size_t ST_OFF  = A2_OFF + (size_t)M_ * C1_ * 2;        // 768 f32
  constexpr size_t SS1_OFF = ST_OFF + (size_t)768 * 4;             // 2*256 f32
  constexpr size_t SS2_OFF = SS1_OFF + (size_t)2 * C0_ * 4;        // 2*128 f32

  int*   idx   = (int*)(ws + IDX_OFF);
  float* wts   = (float*)(ws + WTS_OFF);
  short* W0b   = (short*)(ws + W0B_OFF);
  short* W1b   = (short*)(ws + W1B_OFF);
  float* xyz2p = (float*)(ws + XW_OFF);
  short* h     = (short*)(ws + H_OFF);
  short* a1    = (short*)(ws + A1_OFF);
  short* h1    = (short*)(ws + H1_OFF);
  short* a2    = (short*)(ws + A2_OFF);
  float* st    = (float*)(ws + ST_OFF);   // stats1 = st, stats2 = st + 512
  float* ss1   = (float*)(ws + SS1_OFF);
  float* ss2   = (float*)(ws + SS2_OFF);
  float* outp  = (float*)d_out;

  convw_kernel<<<512, 256, 0, stream>>>(W0, W1, xyz2, W0b, W1b, xyz2p, st);
  topk_kernel<<<B_ * (N_ / 64), 256, 0, stream>>>(xyz1, xyz2p, relw, relb, idx, wts);
  build_h_kernel<<<M_ / 4, 256, 0, stream>>>(pts1, pts2, idx, wts, h);

  gemm_bt_kernel<K2D_><<<dim3(M_ / 128, C0_ / 128), 256, 0, stream>>>(h, W0b, b0, a1, st, C0_);
  stats_final_kernel<<<1, 256, 0, stream>>>(st, C0_, b0, g0, be0, ss1);
  norm1_kernel<<<(size_t)M_ * C0_ / 8 / 256, 256, 0, stream>>>(a1, ss1, h1);

  gemm_bt_kernel<C0_><<<dim3(M_ / 128, C1_ / 128), 256, 0, stream>>>(h1, W1b, b1, a2, st + 512, C1_);
  stats_final_kernel<<<1, 128, 0, stream>>>(st + 512, C1_, b1, g1, be1, ss2);
  norm2_kernel<<<(size_t)M_ * C1_ / 8 / 256, 256, 0, stream>>>(a2, ss2, outp);
}

// Round 5
// 305.999 us; speedup vs baseline: 2.2613x; 1.0487x over previous
//
#include <hip/hip_runtime.h>
#include <stdint.h>
#include <stddef.h>

// Problem constants
#define B_   8
#define N_   8192
#define S_   2048
#define D_   256
#define M_   (B_*N_)     // 65536 total points
#define C0_  256         // MLP[0]
#define C1_  128         // MLP[1]
#define K2D_ 512         // 2*D
#define TS8_ 8           // S-segments (waves) per topk block
#define SEG8_ (S_/TS8_)  // 256

typedef __attribute__((ext_vector_type(8))) short short8;
typedef __attribute__((ext_vector_type(4))) short short4v;
typedef __attribute__((ext_vector_type(4))) float f32x4;
typedef __attribute__((ext_vector_type(2))) float f32x2;

__device__ __forceinline__ short f2bf(float f) {
  unsigned u = __float_as_uint(f);
  u += 0x7fffu + ((u >> 16) & 1u);   // round-to-nearest-even
  return (short)(u >> 16);
}
__device__ __forceinline__ float bf2f(short s) {
  return __uint_as_float(((unsigned)(unsigned short)s) << 16);
}

__device__ __forceinline__ void cp16(const void* g, void* l) {
  __builtin_amdgcn_global_load_lds(
      (__attribute__((address_space(1))) void*)(g),
      (__attribute__((address_space(3))) void*)(l), 16, 0, 0);
}

// ---------------------------------------------------------------------------
// K0: convert W0/W1 to bf16; build component-SoA xyz2p (x|y|z|sumsq streams
// per batch); block 0 zeroes the 768-float stats buffer.
// ---------------------------------------------------------------------------
__global__ void convw_kernel(const float* __restrict__ W0,
                             const float* __restrict__ W1,
                             const float* __restrict__ xyz2,
                             short* __restrict__ W0b, short* __restrict__ W1b,
                             float* __restrict__ xyz2p, float* __restrict__ stats) {
  int i = blockIdx.x * 256 + threadIdx.x;
  if (blockIdx.x == 0) {
    stats[threadIdx.x] = 0.f;
    stats[256 + threadIdx.x] = 0.f;
    stats[512 + threadIdx.x] = 0.f;
  }
  if (i < C0_ * K2D_) W0b[i] = f2bf(W0[i]);
  if (i < C1_ * C0_)  W1b[i] = f2bf(W1[i]);
  if (i < B_ * S_) {
    const int b = i >> 11, s = i & (S_ - 1);
    float x = xyz2[(size_t)i * 3 + 0];
    float y = xyz2[(size_t)i * 3 + 1];
    float z = xyz2[(size_t)i * 3 + 2];
    float ss = __fadd_rn(__fadd_rn(__fmul_rn(x, x), __fmul_rn(y, y)), __fmul_rn(z, z));
    float* xw = xyz2p + (size_t)b * 4 * S_;
    xw[s] = x; xw[S_ + s] = y; xw[2 * S_ + s] = z; xw[3 * S_ + s] = ss;
  }
}

// ---------------------------------------------------------------------------
// K1: top-3 NN + sigmoid relation weights.
// 1024 blocks x 8 waves (512 thr); wave = one 256-candidate segment for 64
// queries (1/lane) -> 32 waves/CU occupancy cap. Packed f32x2 math,
// contract(off) => bit-identical to numpy expression tree. Segment-ordered
// merge reproduces the sequential strict-< scan exactly.
// ---------------------------------------------------------------------------
__global__ __launch_bounds__(512, 8)
void topk_kernel(const float* __restrict__ xyz1, const float* __restrict__ xyz2p,
                 const float* __restrict__ relw, const float* __restrict__ relb,
                 int* __restrict__ idx_out, float* __restrict__ w_out) {
  __shared__ float cd[TS8_][64][3];   // 6 KB
  __shared__ int   ci[TS8_][64][3];   // 6 KB
  const int tid  = threadIdx.x;
  const int lane = tid & 63;
  const int seg  = __builtin_amdgcn_readfirstlane(tid >> 6);
  const int b    = blockIdx.x >> 7;             // 128 blocks per batch
  const int n    = (blockIdx.x & 127) * 64 + lane;

  const float* p = xyz1 + ((size_t)b * N_ + n) * 3;
  const float ax = p[0], ay = p[1], az = p[2];
  const float s1 = __fadd_rn(__fadd_rn(__fmul_rn(ax, ax), __fmul_rn(ay, ay)), __fmul_rn(az, az));

  const float* xw = xyz2p + (size_t)b * 4 * S_;
  const f32x2* XP = (const f32x2*)(xw)           + seg * (SEG8_ / 2);
  const f32x2* YP = (const f32x2*)(xw + S_)      + seg * (SEG8_ / 2);
  const f32x2* ZP = (const f32x2*)(xw + 2 * S_)  + seg * (SEG8_ / 2);
  const f32x2* WP = (const f32x2*)(xw + 3 * S_)  + seg * (SEG8_ / 2);

  float d0 = 3.4e38f, d1 = 3.4e38f, d2 = 3.4e38f;
  int   i0 = 0, i1 = 0, i2 = 0;
  const int sbeg = seg * SEG8_;
  {
    #pragma clang fp contract(off)
    #pragma unroll 4
    for (int pr = 0; pr < SEG8_ / 2; pr++) {
      f32x2 X = XP[pr], Y = YP[pr], Z = ZP[pr], W = WP[pr];
      f32x2 t1 = ax * X;
      f32x2 t2 = ay * Y;
      f32x2 t3 = az * Z;
      f32x2 dt = (t1 + t2) + t3;
      f32x2 e  = s1 + W;
      f32x2 m  = 2.0f * dt;
      f32x2 d  = e - m;
      const float dlo = d.x, dhi = d.y;
      if (fminf(dlo, dhi) < d2) {
        const int s = sbeg + 2 * pr;
        if (dlo < d2) {
          if (dlo < d1) {
            d2 = d1; i2 = i1;
            if (dlo < d0) { d1 = d0; i1 = i0; d0 = dlo; i0 = s; }
            else          { d1 = dlo; i1 = s; }
          } else { d2 = dlo; i2 = s; }
        }
        if (dhi < d2) {
          if (dhi < d1) {
            d2 = d1; i2 = i1;
            if (dhi < d0) { d1 = d0; i1 = i0; d0 = dhi; i0 = s + 1; }
            else          { d1 = dhi; i1 = s + 1; }
          } else { d2 = dhi; i2 = s + 1; }
        }
      }
    }
  }
  cd[seg][lane][0] = d0; cd[seg][lane][1] = d1; cd[seg][lane][2] = d2;
  ci[seg][lane][0] = i0; ci[seg][lane][1] = i1; ci[seg][lane][2] = i2;
  __syncthreads();

  if (tid < 64) {
    float m0 = 3.4e38f, m1 = 3.4e38f, m2 = 3.4e38f;
    int   j0 = 0, j1 = 0, j2 = 0;
    #pragma unroll
    for (int sg = 0; sg < TS8_; sg++) {
      #pragma unroll
      for (int k = 0; k < 3; k++) {
        float d = cd[sg][tid][k];
        int   ix = ci[sg][tid][k];
        if (d < m2) {
          if (d < m1) {
            m2 = m1; j2 = j1;
            if (d < m0) { m1 = m0; j1 = j0; m0 = d; j0 = ix; }
            else        { m1 = d;  j1 = ix; }
          } else { m2 = d; j2 = ix; }
        }
      }
    }
    const float w0r = relw[0], w1r = relw[1], w2r = relw[2], w3r = relw[3], br = relb[0];
    const size_t base = ((size_t)b * N_ + n) * 3;
    float dd[3] = {m0, m1, m2};
    int   ii[3] = {j0, j1, j2};
    #pragma unroll
    for (int k = 0; k < 3; k++) {
      const int s = ii[k];
      float ox = ax - xw[s], oy = ay - xw[S_ + s], oz = az - xw[2 * S_ + s];
      float t = dd[k] * w0r + ox * w1r + oy * w2r + oz * w3r + br;
      float w = 1.0f / (1.0f + expf(-t));
      idx_out[base + k] = s;
      w_out[base + k] = w * (1.0f / 3.0f);
    }
  }
}

// ---------------------------------------------------------------------------
// GEMM1 (fused build_h): a1[M][256](bf16) = h @ W0^T, where h-tile is built
// on the fly: k<256 from p1 (f32->bf16), k>=256 interp = sum_k w_k*p2[idx_k].
// 128x128 tile, 4 waves (2x2), 4x4 frags. Epilogue: bf16 store + per-column
// (sum,sumsq) atomics into stats (bias excluded; folded in stats_final).
// ---------------------------------------------------------------------------
__global__ __launch_bounds__(256, 3)
void gemm1_kernel(const float* __restrict__ p1, const float* __restrict__ p2,
                  const int* __restrict__ idx, const float* __restrict__ wts,
                  const short* __restrict__ Bw, const float* __restrict__ bias,
                  short* __restrict__ Cb, float* __restrict__ stats) {
  __shared__ __align__(16) short sA[128 * 32];
  __shared__ __align__(16) short sB[128 * 32];
  const int tid = threadIdx.x;
  const int lane = tid & 63;
  const int wave = tid >> 6;
  const int wm = wave & 1;
  const int wn = wave >> 1;
  const size_t mbase = (size_t)blockIdx.x * 128;
  const int nbase = blockIdx.y * 128;
  const int lrow = lane >> 2;          // 0..15
  const int lcol = (lane & 3) * 8;     // 0,8,16,24

  f32x4 acc[4][4] = {};

  for (int k0 = 0; k0 < K2D_; k0 += 32) {
    #pragma unroll
    for (int t = 0; t < 2; t++) {
      const int r = wave * 32 + t * 16;
      const int row = (int)mbase + r + lrow;
      cp16(Bw + (size_t)(nbase + r + lrow) * K2D_ + k0 + lcol, &sB[r * 32]);
      float v[8];
      if (k0 < D_) {
        const float* src = p1 + (size_t)row * D_ + k0 + lcol;
        float4 f0 = *(const float4*)src;
        float4 f1 = *(const float4*)(src + 4);
        v[0] = f0.x; v[1] = f0.y; v[2] = f0.z; v[3] = f0.w;
        v[4] = f1.x; v[5] = f1.y; v[6] = f1.z; v[7] = f1.w;
      } else {
        const int c2 = k0 - D_ + lcol;
        const int bb = row >> 13;
        const float* pb = p2 + (size_t)bb * S_ * D_;
        const int i0 = idx[row * 3 + 0], i1 = idx[row * 3 + 1], i2 = idx[row * 3 + 2];
        const float w0 = wts[row * 3 + 0], w1 = wts[row * 3 + 1], w2 = wts[row * 3 + 2];
        const float* q0 = pb + (size_t)i0 * D_ + c2;
        const float* q1 = pb + (size_t)i1 * D_ + c2;
        const float* q2 = pb + (size_t)i2 * D_ + c2;
        float4 a0 = *(const float4*)q0, a1v = *(const float4*)(q0 + 4);
        float4 b0 = *(const float4*)q1, b1v = *(const float4*)(q1 + 4);
        float4 c0 = *(const float4*)q2, c1v = *(const float4*)(q2 + 4);
        v[0] = w0 * a0.x + w1 * b0.x + w2 * c0.x;
        v[1] = w0 * a0.y + w1 * b0.y + w2 * c0.y;
        v[2] = w0 * a0.z + w1 * b0.z + w2 * c0.z;
        v[3] = w0 * a0.w + w1 * b0.w + w2 * c0.w;
        v[4] = w0 * a1v.x + w1 * b1v.x + w2 * c1v.x;
        v[5] = w0 * a1v.y + w1 * b1v.y + w2 * c1v.y;
        v[6] = w0 * a1v.z + w1 * b1v.z + w2 * c1v.z;
        v[7] = w0 * a1v.w + w1 * b1v.w + w2 * c1v.w;
      }
      short8 o;
      #pragma unroll
      for (int e = 0; e < 8; e++) o[e] = f2bf(v[e]);
      *(short8*)&sA[(r + lrow) * 32 + lcol] = o;
    }
    __syncthreads();

    const int mr = lane & 15;
    const int ks = (lane >> 4) * 8;
    short8 af[4], bfr[4];
    #pragma unroll
    for (int i = 0; i < 4; i++) af[i]  = *(const short8*)&sA[(wm * 64 + i * 16 + mr) * 32 + ks];
    #pragma unroll
    for (int j = 0; j < 4; j++) bfr[j] = *(const short8*)&sB[(wn * 64 + j * 16 + mr) * 32 + ks];
    #pragma unroll
    for (int i = 0; i < 4; i++)
      #pragma unroll
      for (int j = 0; j < 4; j++)
        acc[i][j] = __builtin_amdgcn_mfma_f32_16x16x32_bf16(af[i], bfr[j], acc[i][j], 0, 0, 0);
    __syncthreads();
  }

  const int cr = (lane >> 4) * 4;
  const int cc = lane & 15;
  float ps[4], ps2[4];
  #pragma unroll
  for (int j = 0; j < 4; j++) {
    const int col = nbase + wn * 64 + j * 16 + cc;
    const float bv = bias[col];
    float s = 0.f, s2 = 0.f;
    #pragma unroll
    for (int i = 0; i < 4; i++) {
      #pragma unroll
      for (int r = 0; r < 4; r++) {
        const float v = acc[i][j][r];
        s += v; s2 += v * v;
        const size_t row = mbase + wm * 64 + i * 16 + cr + r;
        Cb[row * C0_ + col] = f2bf(v + bv);
      }
    }
    ps[j] = s; ps2[j] = s2;
  }
  #pragma unroll
  for (int j = 0; j < 4; j++) {
    ps[j]  += __shfl_xor(ps[j], 16);  ps[j]  += __shfl_xor(ps[j], 32);
    ps2[j] += __shfl_xor(ps2[j], 16); ps2[j] += __shfl_xor(ps2[j], 32);
  }
  float* sred = (float*)sA;
  if (wm == 1 && lane < 16) {
    #pragma unroll
    for (int j = 0; j < 4; j++) {
      const int c = wn * 64 + j * 16 + lane;
      sred[2 * c] = ps[j]; sred[2 * c + 1] = ps2[j];
    }
  }
  __syncthreads();
  if (wm == 0 && lane < 16) {
    #pragma unroll
    for (int j = 0; j < 4; j++) {
      const int c = wn * 64 + j * 16 + lane;
      atomicAdd(&stats[nbase + c],       ps[j]  + sred[2 * c]);
      atomicAdd(&stats[C0_ + nbase + c], ps2[j] + sred[2 * c + 1]);
    }
  }
}

// ---------------------------------------------------------------------------
// GEMM2 (fused norm1): a2[M][128](bf16) = relu(bn(a1)) @ W1^T. A-tile staged
// manually from a1 bf16 with scale/shift+ReLU applied in flight (ss1).
// ---------------------------------------------------------------------------
__global__ __launch_bounds__(256, 2)
void gemm2_kernel(const short* __restrict__ A, const short* __restrict__ Bw,
                  const float* __restrict__ ssn, const float* __restrict__ bias,
                  short* __restrict__ Cb, float* __restrict__ stats) {
  __shared__ __align__(16) short sA[128 * 32];
  __shared__ __align__(16) short sB[128 * 32];
  const int tid = threadIdx.x;
  const int lane = tid & 63;
  const int wave = tid >> 6;
  const int wm = wave & 1;
  const int wn = wave >> 1;
  const size_t mbase = (size_t)blockIdx.x * 128;
  const int lrow = lane >> 2;
  const int lcol = (lane & 3) * 8;

  f32x4 acc[4][4] = {};

  for (int k0 = 0; k0 < C0_; k0 += 32) {
    float4 sca = *(const float4*)(ssn + k0 + lcol);
    float4 scb = *(const float4*)(ssn + k0 + lcol + 4);
    float4 sha = *(const float4*)(ssn + C0_ + k0 + lcol);
    float4 shb = *(const float4*)(ssn + C0_ + k0 + lcol + 4);
    #pragma unroll
    for (int t = 0; t < 2; t++) {
      const int r = wave * 32 + t * 16;
      const int row = (int)mbase + r + lrow;
      cp16(Bw + (size_t)(r + lrow) * C0_ + k0 + lcol, &sB[r * 32]);
      short8 av = *(const short8*)(A + (size_t)row * C0_ + k0 + lcol);
      float sc[8] = {sca.x, sca.y, sca.z, sca.w, scb.x, scb.y, scb.z, scb.w};
      float sh[8] = {sha.x, sha.y, sha.z, sha.w, shb.x, shb.y, shb.z, shb.w};
      short8 o;
      #pragma unroll
      for (int e = 0; e < 8; e++) {
        float v = bf2f(av[e]) * sc[e] + sh[e];
        o[e] = f2bf(v > 0.f ? v : 0.f);
      }
      *(short8*)&sA[(r + lrow) * 32 + lcol] = o;
    }
    __syncthreads();

    const int mr = lane & 15;
    const int ks = (lane >> 4) * 8;
    short8 af[4], bfr[4];
    #pragma unroll
    for (int i = 0; i < 4; i++) af[i]  = *(const short8*)&sA[(wm * 64 + i * 16 + mr) * 32 + ks];
    #pragma unroll
    for (int j = 0; j < 4; j++) bfr[j] = *(const short8*)&sB[(wn * 64 + j * 16 + mr) * 32 + ks];
    #pragma unroll
    for (int i = 0; i < 4; i++)
      #pragma unroll
      for (int j = 0; j < 4; j++)
        acc[i][j] = __builtin_amdgcn_mfma_f32_16x16x32_bf16(af[i], bfr[j], acc[i][j], 0, 0, 0);
    __syncthreads();
  }

  const int cr = (lane >> 4) * 4;
  const int cc = lane & 15;
  float ps[4], ps2[4];
  #pragma unroll
  for (int j = 0; j < 4; j++) {
    const int col = wn * 64 + j * 16 + cc;
    const float bv = bias[col];
    float s = 0.f, s2 = 0.f;
    #pragma unroll
    for (int i = 0; i < 4; i++) {
      #pragma unroll
      for (int r = 0; r < 4; r++) {
        const float v = acc[i][j][r];
        s += v; s2 += v * v;
        const size_t row = mbase + wm * 64 + i * 16 + cr + r;
        Cb[row * C1_ + col] = f2bf(v + bv);
      }
    }
    ps[j] = s; ps2[j] = s2;
  }
  #pragma unroll
  for (int j = 0; j < 4; j++) {
    ps[j]  += __shfl_xor(ps[j], 16);  ps[j]  += __shfl_xor(ps[j], 32);
    ps2[j] += __shfl_xor(ps2[j], 16); ps2[j] += __shfl_xor(ps2[j], 32);
  }
  float* sred = (float*)sA;
  if (wm == 1 && lane < 16) {
    #pragma unroll
    for (int j = 0; j < 4; j++) {
      const int c = wn * 64 + j * 16 + lane;
      sred[2 * c] = ps[j]; sred[2 * c + 1] = ps2[j];
    }
  }
  __syncthreads();
  if (wm == 0 && lane < 16) {
    #pragma unroll
    for (int j = 0; j < 4; j++) {
      const int c = wn * 64 + j * 16 + lane;
      atomicAdd(&stats[c],       ps[j]  + sred[2 * c]);
      atomicAdd(&stats[C1_ + c], ps2[j] + sred[2 * c + 1]);
    }
  }
}

// ---------------------------------------------------------------------------
// stats_final: scale/shift from accumulated (sum, sumsq); bias folded in.
// ---------------------------------------------------------------------------
__global__ void stats_final_kernel(const float* __restrict__ stats, const int C,
                                   const float* __restrict__ bias,
                                   const float* __restrict__ g, const float* __restrict__ be,
                                   float* __restrict__ ss) {
  const int c = threadIdx.x;
  if (c >= C) return;
  const float inv = 1.0f / (float)M_;
  float m0 = stats[c] * inv;                 // mean excluding bias
  float var = stats[C + c] * inv - m0 * m0;  // bias shift cancels in var
  float mean = m0 + bias[c];
  float sc = g[c] * rsqrtf(var + 1e-5f);
  ss[c] = sc;
  ss[C + c] = be[c] - mean * sc;
}

// ---------------------------------------------------------------------------
// norm2: out(f32) = relu(a2*sc + sh), 8 elems/thread
// ---------------------------------------------------------------------------
__global__ __launch_bounds__(256, 1)
void norm2_kernel(const short* __restrict__ a2, const float* __restrict__ ss,
                  float* __restrict__ out) {
  const size_t t = (size_t)blockIdx.x * 256 + threadIdx.x;
  const size_t base = t * 8;
  const int c = (int)(base & (C1_ - 1));
  short8 v8 = *(const short8*)(a2 + base);
  float vv[8];
  #pragma unroll
  for (int k = 0; k < 8; k++) {
    float v = bf2f(v8[k]) * ss[c + k] + ss[C1_ + c + k];
    vv[k] = v > 0.f ? v : 0.f;
  }
  *(float4*)(out + base)     = make_float4(vv[0], vv[1], vv[2], vv[3]);
  *(float4*)(out + base + 4) = make_float4(vv[4], vv[5], vv[6], vv[7]);
}

// ---------------------------------------------------------------------------
// Launch
// ---------------------------------------------------------------------------
extern "C" void kernel_launch(void* const* d_in, const int* in_sizes, int n_in,
                              void* d_out, int out_size, void* d_ws, size_t ws_size,
                              hipStream_t stream) {
  const float* xyz1 = (const float*)d_in[0];
  const float* xyz2 = (const float*)d_in[1];
  const float* pts1 = (const float*)d_in[2];
  const float* pts2 = (const float*)d_in[3];
  const float* relw = (const float*)d_in[4];
  const float* relb = (const float*)d_in[5];
  const float* W0   = (const float*)d_in[6];
  const float* b0   = (const float*)d_in[7];
  const float* g0   = (const float*)d_in[8];
  const float* be0  = (const float*)d_in[9];
  const float* W1   = (const float*)d_in[10];
  const float* b1   = (const float*)d_in[11];
  const float* g1   = (const float*)d_in[12];
  const float* be1  = (const float*)d_in[13];

  char* ws = (char*)d_ws;
  constexpr size_t IDX_OFF = 0;                                    // M*3 int
  constexpr size_t WTS_OFF = IDX_OFF + (size_t)M_ * 3 * 4;         // M*3 f32
  constexpr size_t W0B_OFF = WTS_OFF + (size_t)M_ * 3 * 4;         // 256*512 bf16
  constexpr size_t W1B_OFF = W0B_OFF + (size_t)C0_ * K2D_ * 2;     // 128*256 bf16
  constexpr size_t XW_OFF  = W1B_OFF + (size_t)C1_ * C0_ * 2;      // B*4*S f32
  constexpr size_t A1_OFF  = XW_OFF + (size_t)B_ * 4 * S_ * 4;     // M*256 bf16
  constexpr size_t A2_OFF  = A1_OFF + (size_t)M_ * C0_ * 2;        // M*128 bf16
  constexpr size_t ST_OFF  = A2_OFF + (size_t)M_ * C1_ * 2;        // 768 f32
  constexpr size_t SS1_OFF = ST_OFF + (size_t)768 * 4;             // 2*256 f32
  constexpr size_t SS2_OFF = SS1_OFF + (size_t)2 * C0_ * 4;        // 2*128 f32

  int*   idx   = (int*)(ws + IDX_OFF);
  float* wts   = (float*)(ws + WTS_OFF);
  short* W0b   = (short*)(ws + W0B_OFF);
  short* W1b   = (short*)(ws + W1B_OFF);
  float* xyz2p = (float*)(ws + XW_OFF);
  short* a1    = (short*)(ws + A1_OFF);
  short* a2    = (short*)(ws + A2_OFF);
  float* st    = (float*)(ws + ST_OFF);   // stats1 = st, stats2 = st + 512
  float* ss1   = (float*)(ws + SS1_OFF);
  float* ss2   = (float*)(ws + SS2_OFF);
  float* outp  = (float*)d_out;

  convw_kernel<<<512, 256, 0, stream>>>(W0, W1, xyz2, W0b, W1b, xyz2p, st);
  topk_kernel<<<B_ * (N_ / 64), 512, 0, stream>>>(xyz1, xyz2p, relw, relb, idx, wts);

  gemm1_kernel<<<dim3(M_ / 128, C0_ / 128), 256, 0, stream>>>(
      pts1, pts2, idx, wts, W0b, b0, a1, st);
  stats_final_kernel<<<1, 256, 0, stream>>>(st, C0_, b0, g0, be0, ss1);

  gemm2_kernel<<<dim3(M_ / 128, 1), 256, 0, stream>>>(a1, W1b, ss1, b1, a2, st + 512);
  stats_final_kernel<<<1, 128, 0, stream>>>(st + 512, C1_, b1, g1, be1, ss2);
  norm2_kernel<<<(size_t)M_ * C1_ / 8 / 256, 256, 0, stream>>>(a2, ss2, outp);
}

// Round 6
// 292.131 us; speedup vs baseline: 2.3686x; 1.0475x over previous
//
#include <hip/hip_runtime.h>
#include <stdint.h>
#include <stddef.h>

// Problem constants
#define B_   8
#define N_   8192
#define S_   2048
#define D_   256
#define M_   (B_*N_)     // 65536 total points
#define C0_  256         // MLP[0]
#define C1_  128         // MLP[1]
#define K2D_ 512         // 2*D
#define TS8_ 8           // S-segments (waves) per topk block
#define SEG8_ (S_/TS8_)  // 256
#define SWP_ 264         // padded LDS row stride (shorts) for W1 in gemm2

typedef __attribute__((ext_vector_type(8))) short short8;
typedef __attribute__((ext_vector_type(4))) float f32x4;
typedef __attribute__((ext_vector_type(2))) float f32x2;

__device__ __forceinline__ short f2bf(float f) {
  unsigned u = __float_as_uint(f);
  u += 0x7fffu + ((u >> 16) & 1u);   // round-to-nearest-even
  return (short)(u >> 16);
}
__device__ __forceinline__ float bf2f(short s) {
  return __uint_as_float(((unsigned)(unsigned short)s) << 16);
}

__device__ __forceinline__ void cp16(const void* g, void* l) {
  __builtin_amdgcn_global_load_lds(
      (__attribute__((address_space(1))) void*)(g),
      (__attribute__((address_space(3))) void*)(l), 16, 0, 0);
}

// ---------------------------------------------------------------------------
// K0: convert W0/W1 to bf16; build component-SoA xyz2p; zero stats buffer.
// ---------------------------------------------------------------------------
__global__ void convw_kernel(const float* __restrict__ W0,
                             const float* __restrict__ W1,
                             const float* __restrict__ xyz2,
                             short* __restrict__ W0b, short* __restrict__ W1b,
                             float* __restrict__ xyz2p, float* __restrict__ stats) {
  int i = blockIdx.x * 256 + threadIdx.x;
  if (blockIdx.x == 0) {
    stats[threadIdx.x] = 0.f;
    stats[256 + threadIdx.x] = 0.f;
    stats[512 + threadIdx.x] = 0.f;
  }
  if (i < C0_ * K2D_) W0b[i] = f2bf(W0[i]);
  if (i < C1_ * C0_)  W1b[i] = f2bf(W1[i]);
  if (i < B_ * S_) {
    const int b = i >> 11, s = i & (S_ - 1);
    float x = xyz2[(size_t)i * 3 + 0];
    float y = xyz2[(size_t)i * 3 + 1];
    float z = xyz2[(size_t)i * 3 + 2];
    float ss = __fadd_rn(__fadd_rn(__fmul_rn(x, x), __fmul_rn(y, y)), __fmul_rn(z, z));
    float* xw = xyz2p + (size_t)b * 4 * S_;
    xw[s] = x; xw[S_ + s] = y; xw[2 * S_ + s] = z; xw[3 * S_ + s] = ss;
  }
}

// ---------------------------------------------------------------------------
// K1: top-3 NN + sigmoid relation weights (unchanged from R5).
// ---------------------------------------------------------------------------
__global__ __launch_bounds__(512, 8)
void topk_kernel(const float* __restrict__ xyz1, const float* __restrict__ xyz2p,
                 const float* __restrict__ relw, const float* __restrict__ relb,
                 int* __restrict__ idx_out, float* __restrict__ w_out) {
  __shared__ float cd[TS8_][64][3];
  __shared__ int   ci[TS8_][64][3];
  const int tid  = threadIdx.x;
  const int lane = tid & 63;
  const int seg  = __builtin_amdgcn_readfirstlane(tid >> 6);
  const int b    = blockIdx.x >> 7;
  const int n    = (blockIdx.x & 127) * 64 + lane;

  const float* p = xyz1 + ((size_t)b * N_ + n) * 3;
  const float ax = p[0], ay = p[1], az = p[2];
  const float s1 = __fadd_rn(__fadd_rn(__fmul_rn(ax, ax), __fmul_rn(ay, ay)), __fmul_rn(az, az));

  const float* xw = xyz2p + (size_t)b * 4 * S_;
  const f32x2* XP = (const f32x2*)(xw)           + seg * (SEG8_ / 2);
  const f32x2* YP = (const f32x2*)(xw + S_)      + seg * (SEG8_ / 2);
  const f32x2* ZP = (const f32x2*)(xw + 2 * S_)  + seg * (SEG8_ / 2);
  const f32x2* WP = (const f32x2*)(xw + 3 * S_)  + seg * (SEG8_ / 2);

  float d0 = 3.4e38f, d1 = 3.4e38f, d2 = 3.4e38f;
  int   i0 = 0, i1 = 0, i2 = 0;
  const int sbeg = seg * SEG8_;
  {
    #pragma clang fp contract(off)
    #pragma unroll 4
    for (int pr = 0; pr < SEG8_ / 2; pr++) {
      f32x2 X = XP[pr], Y = YP[pr], Z = ZP[pr], W = WP[pr];
      f32x2 t1 = ax * X;
      f32x2 t2 = ay * Y;
      f32x2 t3 = az * Z;
      f32x2 dt = (t1 + t2) + t3;
      f32x2 e  = s1 + W;
      f32x2 m  = 2.0f * dt;
      f32x2 d  = e - m;
      const float dlo = d.x, dhi = d.y;
      if (fminf(dlo, dhi) < d2) {
        const int s = sbeg + 2 * pr;
        if (dlo < d2) {
          if (dlo < d1) {
            d2 = d1; i2 = i1;
            if (dlo < d0) { d1 = d0; i1 = i0; d0 = dlo; i0 = s; }
            else          { d1 = dlo; i1 = s; }
          } else { d2 = dlo; i2 = s; }
        }
        if (dhi < d2) {
          if (dhi < d1) {
            d2 = d1; i2 = i1;
            if (dhi < d0) { d1 = d0; i1 = i0; d0 = dhi; i0 = s + 1; }
            else          { d1 = dhi; i1 = s + 1; }
          } else { d2 = dhi; i2 = s + 1; }
        }
      }
    }
  }
  cd[seg][lane][0] = d0; cd[seg][lane][1] = d1; cd[seg][lane][2] = d2;
  ci[seg][lane][0] = i0; ci[seg][lane][1] = i1; ci[seg][lane][2] = i2;
  __syncthreads();

  if (tid < 64) {
    float m0 = 3.4e38f, m1 = 3.4e38f, m2 = 3.4e38f;
    int   j0 = 0, j1 = 0, j2 = 0;
    #pragma unroll
    for (int sg = 0; sg < TS8_; sg++) {
      #pragma unroll
      for (int k = 0; k < 3; k++) {
        float d = cd[sg][tid][k];
        int   ix = ci[sg][tid][k];
        if (d < m2) {
          if (d < m1) {
            m2 = m1; j2 = j1;
            if (d < m0) { m1 = m0; j1 = j0; m0 = d; j0 = ix; }
            else        { m1 = d;  j1 = ix; }
          } else { m2 = d; j2 = ix; }
        }
      }
    }
    const float w0r = relw[0], w1r = relw[1], w2r = relw[2], w3r = relw[3], br = relb[0];
    const size_t base = ((size_t)b * N_ + n) * 3;
    float dd[3] = {m0, m1, m2};
    int   ii[3] = {j0, j1, j2};
    #pragma unroll
    for (int k = 0; k < 3; k++) {
      const int s = ii[k];
      float ox = ax - xw[s], oy = ay - xw[S_ + s], oz = az - xw[2 * S_ + s];
      float t = dd[k] * w0r + ox * w1r + oy * w2r + oz * w3r + br;
      float w = 1.0f / (1.0f + expf(-t));
      idx_out[base + k] = s;
      w_out[base + k] = w * (1.0f / 3.0f);
    }
  }
}

// ---------------------------------------------------------------------------
// GEMM1 (fused build_h): a1[M][256](bf16) = h @ W0^T.
// Full-N tile: 128 rows x 256 cols per block (grid 512 = 2 blocks/CU, no tail).
// Waves 2x2: wm = M-half (64 rows), wn = N-half (128 cols), acc 4x8 frags.
// Register-prefetch pipeline: next A-slice gathers + double-buffered cp16 sB
// issued right after barrier-1 -> overlap the 32-MFMA phase.
// ---------------------------------------------------------------------------
__global__ __launch_bounds__(256, 2)
void gemm1_kernel(const float* __restrict__ p1, const float* __restrict__ p2,
                  const int* __restrict__ idx, const float* __restrict__ wts,
                  const short* __restrict__ Bw, const float* __restrict__ bias,
                  short* __restrict__ Cb, float* __restrict__ stats) {
  __shared__ __align__(16) short sA[128 * 32];
  __shared__ __align__(16) short sB[2][256 * 32];
  const int tid = threadIdx.x;
  const int lane = tid & 63;
  const int wave = tid >> 6;
  const int wm = wave & 1;
  const int wn = wave >> 1;
  const size_t mbase = (size_t)blockIdx.x * 128;
  const int lrow = lane >> 2;          // 0..15
  const int lcol = (lane & 3) * 8;     // 0,8,16,24

  // Hoisted per-thread staging-row metadata (2 rows per thread, fixed over K)
  int rowg[2]; int ia[2][3]; float wa[2][3]; const float* pbase[2];
  #pragma unroll
  for (int t = 0; t < 2; t++) {
    const int row = (int)mbase + wave * 32 + t * 16 + lrow;
    rowg[t] = row;
    pbase[t] = p2 + (size_t)(row >> 13) * S_ * D_;
    ia[t][0] = idx[row * 3 + 0]; ia[t][1] = idx[row * 3 + 1]; ia[t][2] = idx[row * 3 + 2];
    wa[t][0] = wts[row * 3 + 0]; wa[t][1] = wts[row * 3 + 1]; wa[t][2] = wts[row * 3 + 2];
  }

  f32x4 acc[4][8] = {};
  float4 v[2][6];

  #define LOAD_A(K0)                                                          \
    if ((K0) < D_) {                                                          \
      _Pragma("unroll")                                                       \
      for (int t = 0; t < 2; t++) {                                           \
        const float* src = p1 + (size_t)rowg[t] * D_ + (K0) + lcol;           \
        v[t][0] = *(const float4*)src; v[t][1] = *(const float4*)(src + 4);   \
      }                                                                       \
    } else {                                                                  \
      const int c2 = (K0) - D_ + lcol;                                        \
      _Pragma("unroll")                                                       \
      for (int t = 0; t < 2; t++) {                                           \
        const float* q0 = pbase[t] + (size_t)ia[t][0] * D_ + c2;              \
        const float* q1 = pbase[t] + (size_t)ia[t][1] * D_ + c2;              \
        const float* q2 = pbase[t] + (size_t)ia[t][2] * D_ + c2;              \
        v[t][0] = *(const float4*)q0; v[t][1] = *(const float4*)(q0 + 4);     \
        v[t][2] = *(const float4*)q1; v[t][3] = *(const float4*)(q1 + 4);     \
        v[t][4] = *(const float4*)q2; v[t][5] = *(const float4*)(q2 + 4);     \
      }                                                                       \
    }

  #define STAGE_B(K0, BUF)                                                    \
    _Pragma("unroll")                                                         \
    for (int t = 0; t < 4; t++) {                                             \
      const int r = wave * 64 + t * 16;                                       \
      cp16(Bw + (size_t)(r + lrow) * K2D_ + (K0) + lcol, &sB[BUF][r * 32]);   \
    }

  LOAD_A(0);
  STAGE_B(0, 0);

  for (int k0 = 0, it = 0; k0 < K2D_; k0 += 32, it++) {
    // build sA(k0) from prefetched registers
    #pragma unroll
    for (int t = 0; t < 2; t++) {
      const int r = wave * 32 + t * 16;
      float fv[8];
      if (k0 < D_) {
        fv[0] = v[t][0].x; fv[1] = v[t][0].y; fv[2] = v[t][0].z; fv[3] = v[t][0].w;
        fv[4] = v[t][1].x; fv[5] = v[t][1].y; fv[6] = v[t][1].z; fv[7] = v[t][1].w;
      } else {
        fv[0] = wa[t][0] * v[t][0].x + wa[t][1] * v[t][2].x + wa[t][2] * v[t][4].x;
        fv[1] = wa[t][0] * v[t][0].y + wa[t][1] * v[t][2].y + wa[t][2] * v[t][4].y;
        fv[2] = wa[t][0] * v[t][0].z + wa[t][1] * v[t][2].z + wa[t][2] * v[t][4].z;
        fv[3] = wa[t][0] * v[t][0].w + wa[t][1] * v[t][2].w + wa[t][2] * v[t][4].w;
        fv[4] = wa[t][0] * v[t][1].x + wa[t][1] * v[t][3].x + wa[t][2] * v[t][5].x;
        fv[5] = wa[t][0] * v[t][1].y + wa[t][1] * v[t][3].y + wa[t][2] * v[t][5].y;
        fv[6] = wa[t][0] * v[t][1].z + wa[t][1] * v[t][3].z + wa[t][2] * v[t][5].z;
        fv[7] = wa[t][0] * v[t][1].w + wa[t][1] * v[t][3].w + wa[t][2] * v[t][5].w;
      }
      short8 o;
      #pragma unroll
      for (int e = 0; e < 8; e++) o[e] = f2bf(fv[e]);
      *(short8*)&sA[(r + lrow) * 32 + lcol] = o;
    }
    __syncthreads();   // sA(k0) written; sB[it&1](k0) cp16s drained

    const int kn = k0 + 32;
    if (kn < K2D_) {
      STAGE_B(kn, (it + 1) & 1);
      LOAD_A(kn);
    }

    const int mr = lane & 15;
    const int ks = (lane >> 4) * 8;
    short8 af[4], bfr[8];
    #pragma unroll
    for (int i = 0; i < 4; i++) af[i]  = *(const short8*)&sA[(wm * 64 + i * 16 + mr) * 32 + ks];
    #pragma unroll
    for (int j = 0; j < 8; j++) bfr[j] = *(const short8*)&sB[it & 1][(wn * 128 + j * 16 + mr) * 32 + ks];
    #pragma unroll
    for (int i = 0; i < 4; i++)
      #pragma unroll
      for (int j = 0; j < 8; j++)
        acc[i][j] = __builtin_amdgcn_mfma_f32_16x16x32_bf16(af[i], bfr[j], acc[i][j], 0, 0, 0);
    __syncthreads();   // LDS consumed; prefetches for kn drained here (post-MFMA)
  }
  #undef LOAD_A
  #undef STAGE_B

  // Epilogue: bf16 store + per-column (sum,sumsq) -> stats (bias excluded)
  const int cr = (lane >> 4) * 4;
  const int cc = lane & 15;
  float ps[8], ps2[8];
  #pragma unroll
  for (int j = 0; j < 8; j++) {
    const int col = wn * 128 + j * 16 + cc;
    const float bv = bias[col];
    float s = 0.f, s2 = 0.f;
    #pragma unroll
    for (int i = 0; i < 4; i++) {
      #pragma unroll
      for (int r = 0; r < 4; r++) {
        const float vv = acc[i][j][r];
        s += vv; s2 += vv * vv;
        const size_t row = mbase + wm * 64 + i * 16 + cr + r;
        Cb[row * C0_ + col] = f2bf(vv + bv);
      }
    }
    ps[j] = s; ps2[j] = s2;
  }
  #pragma unroll
  for (int j = 0; j < 8; j++) {
    ps[j]  += __shfl_xor(ps[j], 16);  ps[j]  += __shfl_xor(ps[j], 32);
    ps2[j] += __shfl_xor(ps2[j], 16); ps2[j] += __shfl_xor(ps2[j], 32);
  }
  float* sred = (float*)sA;   // reuse: 256 cols x {s,s2} = 2 KB
  if (wm == 1 && lane < 16) {
    #pragma unroll
    for (int j = 0; j < 8; j++) {
      const int c = wn * 128 + j * 16 + lane;
      sred[2 * c] = ps[j]; sred[2 * c + 1] = ps2[j];
    }
  }
  __syncthreads();
  if (wm == 0 && lane < 16) {
    #pragma unroll
    for (int j = 0; j < 8; j++) {
      const int c = wn * 128 + j * 16 + lane;
      atomicAdd(&stats[c],       ps[j]  + sred[2 * c]);
      atomicAdd(&stats[C0_ + c], ps2[j] + sred[2 * c + 1]);
    }
  }
}

// ---------------------------------------------------------------------------
// GEMM2 (fused norm1): a2[M][128](bf16) = relu(bn(a1)) @ W1^T.
// W1 (64 KB) loaded to LDS once (row stride padded to 264 shorts -> 2-way
// bank aliasing only). K-loop has ZERO barriers: A-frags read directly from
// global (coalesced 16B) with BN+ReLU in registers. Wave w owns 32 rows.
// ---------------------------------------------------------------------------
__global__ __launch_bounds__(256, 2)
void gemm2_kernel(const short* __restrict__ A, const short* __restrict__ Bw,
                  const float* __restrict__ ssn, const float* __restrict__ bias,
                  short* __restrict__ Cb, float* __restrict__ stats) {
  __shared__ __align__(16) short sW[C1_ * SWP_];  // 128 x 264 shorts = 66 KB
  __shared__ float sred[3 * 256];
  const int tid = threadIdx.x;
  const int lane = tid & 63;
  const int wave = tid >> 6;
  const size_t mbase = (size_t)blockIdx.x * 128;

  // Load all of W1b into padded LDS (coalesced 16B reads, manual ds_write)
  #pragma unroll
  for (int i = 0; i < 16; i++) {
    const int flat = i * 256 + tid;       // 16B-block index, 0..4095
    const int n = flat >> 5;              // W1 row (32 blocks of 8 shorts each)
    const int kb = flat & 31;
    *(short8*)&sW[n * SWP_ + kb * 8] = *(const short8*)(Bw + (size_t)flat * 8);
  }
  __syncthreads();

  f32x4 acc[2][8] = {};
  const int mr = lane & 15;
  const int ksq = (lane >> 4) * 8;

  for (int k0 = 0; k0 < C0_; k0 += 32) {
    const int kk = k0 + ksq;
    float4 sc0 = *(const float4*)(ssn + kk);
    float4 sc1 = *(const float4*)(ssn + kk + 4);
    float4 sh0 = *(const float4*)(ssn + C0_ + kk);
    float4 sh1 = *(const float4*)(ssn + C0_ + kk + 4);
    const float sc[8] = {sc0.x, sc0.y, sc0.z, sc0.w, sc1.x, sc1.y, sc1.z, sc1.w};
    const float sh[8] = {sh0.x, sh0.y, sh0.z, sh0.w, sh1.x, sh1.y, sh1.z, sh1.w};
    short8 af[2];
    #pragma unroll
    for (int i = 0; i < 2; i++) {
      const size_t row = mbase + wave * 32 + i * 16 + mr;
      short8 av = *(const short8*)(A + row * C0_ + kk);
      short8 o;
      #pragma unroll
      for (int e = 0; e < 8; e++) {
        float f = bf2f(av[e]) * sc[e] + sh[e];
        o[e] = f2bf(f > 0.f ? f : 0.f);
      }
      af[i] = o;
    }
    short8 bf8[8];
    #pragma unroll
    for (int j = 0; j < 8; j++) bf8[j] = *(const short8*)&sW[(j * 16 + mr) * SWP_ + kk];
    #pragma unroll
    for (int i = 0; i < 2; i++)
      #pragma unroll
      for (int j = 0; j < 8; j++)
        acc[i][j] = __builtin_amdgcn_mfma_f32_16x16x32_bf16(af[i], bf8[j], acc[i][j], 0, 0, 0);
  }

  // Epilogue: bf16 store + per-column (sum,sumsq) -> stats
  const int cr = (lane >> 4) * 4;
  const int cc = lane & 15;
  float ps[8], ps2[8];
  #pragma unroll
  for (int j = 0; j < 8; j++) {
    const int col = j * 16 + cc;
    const float bv = bias[col];
    float s = 0.f, s2 = 0.f;
    #pragma unroll
    for (int i = 0; i < 2; i++) {
      #pragma unroll
      for (int r = 0; r < 4; r++) {
        const float vv = acc[i][j][r];
        s += vv; s2 += vv * vv;
        const size_t row = mbase + wave * 32 + i * 16 + cr + r;
        Cb[row * C1_ + col] = f2bf(vv + bv);
      }
    }
    ps[j] = s; ps2[j] = s2;
  }
  #pragma unroll
  for (int j = 0; j < 8; j++) {
    ps[j]  += __shfl_xor(ps[j], 16);  ps[j]  += __shfl_xor(ps[j], 32);
    ps2[j] += __shfl_xor(ps2[j], 16); ps2[j] += __shfl_xor(ps2[j], 32);
  }
  if (wave > 0 && lane < 16) {
    #pragma unroll
    for (int j = 0; j < 8; j++) {
      const int c = j * 16 + lane;
      sred[(wave - 1) * 256 + c]       = ps[j];
      sred[(wave - 1) * 256 + 128 + c] = ps2[j];
    }
  }
  __syncthreads();
  if (wave == 0 && lane < 16) {
    #pragma unroll
    for (int j = 0; j < 8; j++) {
      const int c = j * 16 + lane;
      float s  = ps[j]  + sred[c]       + sred[256 + c]       + sred[512 + c];
      float s2 = ps2[j] + sred[128 + c] + sred[256 + 128 + c] + sred[512 + 128 + c];
      atomicAdd(&stats[c],       s);
      atomicAdd(&stats[C1_ + c], s2);
    }
  }
}

// ---------------------------------------------------------------------------
// stats_final: scale/shift from accumulated (sum, sumsq); bias folded in.
// ---------------------------------------------------------------------------
__global__ void stats_final_kernel(const float* __restrict__ stats, const int C,
                                   const float* __restrict__ bias,
                                   const float* __restrict__ g, const float* __restrict__ be,
                                   float* __restrict__ ss) {
  const int c = threadIdx.x;
  if (c >= C) return;
  const float inv = 1.0f / (float)M_;
  float m0 = stats[c] * inv;
  float var = stats[C + c] * inv - m0 * m0;
  float mean = m0 + bias[c];
  float sc = g[c] * rsqrtf(var + 1e-5f);
  ss[c] = sc;
  ss[C + c] = be[c] - mean * sc;
}

// ---------------------------------------------------------------------------
// norm2: out(f32) = relu(a2*sc + sh), 8 elems/thread
// ---------------------------------------------------------------------------
__global__ __launch_bounds__(256, 1)
void norm2_kernel(const short* __restrict__ a2, const float* __restrict__ ss,
                  float* __restrict__ out) {
  const size_t t = (size_t)blockIdx.x * 256 + threadIdx.x;
  const size_t base = t * 8;
  const int c = (int)(base & (C1_ - 1));
  short8 v8 = *(const short8*)(a2 + base);
  float vv[8];
  #pragma unroll
  for (int k = 0; k < 8; k++) {
    float v = bf2f(v8[k]) * ss[c + k] + ss[C1_ + c + k];
    vv[k] = v > 0.f ? v : 0.f;
  }
  *(float4*)(out + base)     = make_float4(vv[0], vv[1], vv[2], vv[3]);
  *(float4*)(out + base + 4) = make_float4(vv[4], vv[5], vv[6], vv[7]);
}

// ---------------------------------------------------------------------------
// Launch
// ---------------------------------------------------------------------------
extern "C" void kernel_launch(void* const* d_in, const int* in_sizes, int n_in,
                              void* d_out, int out_size, void* d_ws, size_t ws_size,
                              hipStream_t stream) {
  const float* xyz1 = (const float*)d_in[0];
  const float* xyz2 = (const float*)d_in[1];
  const float* pts1 = (const float*)d_in[2];
  const float* pts2 = (const float*)d_in[3];
  const float* relw = (const float*)d_in[4];
  const float* relb = (const float*)d_in[5];
  const float* W0   = (const float*)d_in[6];
  const float* b0   = (const float*)d_in[7];
  const float* g0   = (const float*)d_in[8];
  const float* be0  = (const float*)d_in[9];
  const float* W1   = (const float*)d_in[10];
  const float* b1   = (const float*)d_in[11];
  const float* g1   = (const float*)d_in[12];
  const float* be1  = (const float*)d_in[13];

  char* ws = (char*)d_ws;
  constexpr size_t IDX_OFF = 0;                                    // M*3 int
  constexpr size_t WTS_OFF = IDX_OFF + (size_t)M_ * 3 * 4;         // M*3 f32
  constexpr size_t W0B_OFF = WTS_OFF + (size_t)M_ * 3 * 4;         // 256*512 bf16
  constexpr size_t W1B_OFF = W0B_OFF + (size_t)C0_ * K2D_ * 2;     // 128*256 bf16
  constexpr size_t XW_OFF  = W1B_OFF + (size_t)C1_ * C0_ * 2;      // B*4*S f32
  constexpr size_t A1_OFF  = XW_OFF + (size_t)B_ * 4 * S_ * 4;     // M*256 bf16
  constexpr size_t A2_OFF  = A1_OFF + (size_t)M_ * C0_ * 2;        // M*128 bf16
  constexpr size_t ST_OFF  = A2_OFF + (size_t)M_ * C1_ * 2;        // 768 f32
  constexpr size_t SS1_OFF = ST_OFF + (size_t)768 * 4;             // 2*256 f32
  constexpr size_t SS2_OFF = SS1_OFF + (size_t)2 * C0_ * 4;        // 2*128 f32

  int*   idx   = (int*)(ws + IDX_OFF);
  float* wts   = (float*)(ws + WTS_OFF);
  short* W0b   = (short*)(ws + W0B_OFF);
  short* W1b   = (short*)(ws + W1B_OFF);
  float* xyz2p = (float*)(ws + XW_OFF);
  short* a1    = (short*)(ws + A1_OFF);
  short* a2    = (short*)(ws + A2_OFF);
  float* st    = (float*)(ws + ST_OFF);   // stats1 = st, stats2 = st + 512
  float* ss1   = (float*)(ws + SS1_OFF);
  float* ss2   = (float*)(ws + SS2_OFF);
  float* outp  = (float*)d_out;

  convw_kernel<<<512, 256, 0, stream>>>(W0, W1, xyz2, W0b, W1b, xyz2p, st);
  topk_kernel<<<B_ * (N_ / 64), 512, 0, stream>>>(xyz1, xyz2p, relw, relb, idx, wts);

  gemm1_kernel<<<M_ / 128, 256, 0, stream>>>(pts1, pts2, idx, wts, W0b, b0, a1, st);
  stats_final_kernel<<<1, 256, 0, stream>>>(st, C0_, b0, g0, be0, ss1);

  gemm2_kernel<<<M_ / 128, 256, 0, stream>>>(a1, W1b, ss1, b1, a2, st + 512);
  stats_final_kernel<<<1, 128, 0, stream>>>(st + 512, C1_, b1, g1, be1, ss2);
  norm2_kernel<<<(size_t)M_ * C1_ / 8 / 256, 256, 0, stream>>>(a2, ss2, outp);
}